// Round 9
// baseline (451.463 us; speedup 1.0000x reference)
//
#include <hip/hip_runtime.h>

typedef __attribute__((ext_vector_type(4))) float f32x4;
typedef __attribute__((ext_vector_type(8))) short short8;

#define B_ 4
#define N_ 8192
#define E_ 131072
#define R_ 16
#define H_ 128
#define OUT_ 32
#define NKEYS (B_*N_*R_)   /* 524288 */
#define NEDGE (B_*E_)      /* 524288 */

__device__ __forceinline__ unsigned short f2bf(float f){
  unsigned int u = __float_as_uint(f);
  u = (u + 0x7fffu + ((u>>16)&1u)) >> 16;
  return (unsigned short)u;
}
__device__ __forceinline__ float bfh(unsigned u, int hi){
  return __uint_as_float(hi ? (u & 0xffff0000u) : (u << 16));
}
__device__ __forceinline__ unsigned cvtpk(float lo, float hi){
  unsigned r;
  asm("v_cvt_pk_bf16_f32 %0, %1, %2" : "=v"(r) : "v"(lo), "v"(hi));
  return r;
}

// ---------------- CSR build: key = node*16 + rel, node = b*8192+dst -------

__global__ void hist_k(const int* __restrict__ et, const int* __restrict__ ec,
                       int* __restrict__ cnt){
  int e = blockIdx.x*256 + threadIdx.x;
  int b = e >> 17;                  // E = 2^17
  int dst = et[2*e+1];
  int r  = ec[e];
  atomicAdd(&cnt[(((b<<13)+dst)<<4) + r], 1);
}

// pass A: per-block exclusive scans of cnt values AND of (cnt!=0) flags
__global__ void scanA_k(const int* __restrict__ cnt,
                        int* __restrict__ offp, int* __restrict__ cidxp,
                        int* __restrict__ bsumV, int* __restrict__ bsumF){
  __shared__ int ldsV[256], ldsF[256];
  int t = threadIdx.x;
  int base = blockIdx.x*1024 + t*4;
  int4 v = *(const int4*)(cnt + base);
  int4 f; f.x = v.x!=0; f.y = v.y!=0; f.z = v.z!=0; f.w = v.w!=0;
  ldsV[t] = v.x+v.y+v.z+v.w;
  ldsF[t] = f.x+f.y+f.z+f.w;
  __syncthreads();
  for (int off=1; off<256; off<<=1){
    int xv = (t>=off) ? ldsV[t-off] : 0;
    int xf = (t>=off) ? ldsF[t-off] : 0;
    __syncthreads();
    ldsV[t] += xv; ldsF[t] += xf;
    __syncthreads();
  }
  if (t==255){ bsumV[blockIdx.x] = ldsV[255]; bsumF[blockIdx.x] = ldsF[255]; }
  int pv = (t==0) ? 0 : ldsV[t-1];
  int pf = (t==0) ? 0 : ldsF[t-1];
  int4 ov; ov.x = pv; ov.y = ov.x+v.x; ov.z = ov.y+v.y; ov.w = ov.z+v.z;
  int4 of; of.x = pf; of.y = of.x+f.x; of.z = of.y+f.y; of.w = of.z+f.z;
  *(int4*)(offp  + base) = ov;
  *(int4*)(cidxp + base) = of;
}

// pass B: single-block scan of one 512-entry bsum array (grid=2: V then F)
__global__ void scanB_k(int* __restrict__ bsumV, int* __restrict__ bsumF){
  int* bs = blockIdx.x ? bsumF : bsumV;
  __shared__ int lds[256];
  int t = threadIdx.x;
  int2 v = *(const int2*)(bs + t*2);
  lds[t] = v.x+v.y;
  __syncthreads();
  for (int off=1; off<256; off<<=1){
    int x = (t>=off) ? lds[t-off] : 0;
    __syncthreads();
    lds[t] += x;
    __syncthreads();
  }
  int pre = (t==0) ? 0 : lds[t-1];
  int2 o; o.x = pre; o.y = pre + v.x;
  *(int2*)(bs + t*2) = o;
}

// pass C: finalize off (starts), cmap, and keydesc.xy = {start, cnt<<20|cm}
__global__ void scanC_k(const int* __restrict__ offp, const int* __restrict__ cidxp,
                        const int* __restrict__ bsumV, const int* __restrict__ bsumF,
                        const int* __restrict__ cnt,
                        int* __restrict__ off, int* __restrict__ cmap,
                        uint4* __restrict__ kdesc){
  int t = threadIdx.x;
  int base = blockIdx.x*1024 + t*4;
  int addV = bsumV[blockIdx.x];
  int addF = bsumF[blockIdx.x] + 1;      // +1: slot 0 is the zero block
  int4 o  = *(const int4*)(offp + base);
  o.x+=addV; o.y+=addV; o.z+=addV; o.w+=addV;
  *(int4*)(off + base) = o;
  int4 cx = *(const int4*)(cidxp + base);
  int4 cv = *(const int4*)(cnt + base);
  int4 cm;
  cm.x = cv.x ? cx.x+addF : 0;
  cm.y = cv.y ? cx.y+addF : 0;
  cm.z = cv.z ? cx.z+addF : 0;
  cm.w = cv.w ? cx.w+addF : 0;
  *(int4*)(cmap + base) = cm;
  *(int2*)&kdesc[base+0].x = make_int2(o.x, (cv.x<<20)|cm.x);
  *(int2*)&kdesc[base+1].x = make_int2(o.y, (cv.y<<20)|cm.y);
  *(int2*)&kdesc[base+2].x = make_int2(o.z, (cv.z<<20)|cm.z);
  *(int2*)&kdesc[base+3].x = make_int2(o.w, (cv.w<<20)|cm.w);
}

// fill consumes off (start -> end) via atomicAdd; first edge also lands in
// keydesc.zw = {src0, mask0}.
__global__ void fill_k(const int* __restrict__ et, const int* __restrict__ ec,
                       const float* __restrict__ me, int* __restrict__ off,
                       uint2* __restrict__ erec, uint4* __restrict__ kdesc){
  int e = blockIdx.x*256 + threadIdx.x;
  int b = e >> 17;
  int src = et[2*e];
  int dst = et[2*e+1];
  int r  = ec[e];
  int key = (((b<<13)+dst)<<4) + r;
  unsigned mbits = __float_as_uint(me[e]);
  int pos = atomicAdd(&off[key], 1);
  erec[pos] = make_uint2((unsigned)src, mbits);
  int start = (int)kdesc[key].x;
  if (pos == start)
    *(uint2*)&kdesc[key].z = make_uint2((unsigned)src, mbits);
}

// ---------------- feature prep (embed + 3x W-transpose + zero slot) -------

__global__ void prep_k(const int* __restrict__ cls, const float* __restrict__ emb,
                       const float* __restrict__ W1, const float* __restrict__ W2,
                       const float* __restrict__ W3,
                       unsigned short* __restrict__ h,
                       unsigned short* __restrict__ W1t,
                       unsigned short* __restrict__ W2t,
                       unsigned short* __restrict__ W3t,
                       unsigned short* __restrict__ aggc){
  int t = blockIdx.x*256 + threadIdx.x;
  if (blockIdx.x == 0 && threadIdx.x < 16) {
    *(uint4*)((char*)aggc + threadIdx.x*16) = make_uint4(0,0,0,0);  // zero slot
  }
  if (t < B_*N_*32) {
    int node = t>>5, c = t&31;
    int cl = cls[node];
    float4 v = *(const float4*)(emb + cl*H_ + c*4);
    uint2 o;
    o.x = f2bf(v.x) | ((unsigned int)f2bf(v.y)<<16);
    o.y = f2bf(v.z) | ((unsigned int)f2bf(v.w)<<16);
    *(uint2*)(h + node*H_ + c*4) = o;
  } else {
    int u = t - B_*N_*32;
    if (u < R_*H_*H_) {
      int k = u & 127, n = (u>>7) & 127, r = u >> 14;
      W1t[u] = f2bf(W1[(r*H_ + k)*H_ + n]);
    } else if (u < 2*R_*H_*H_) {
      int u2 = u - R_*H_*H_;
      int k = u2 & 127, n = (u2>>7) & 127, r = u2 >> 14;
      W2t[u2] = f2bf(W2[(r*H_ + k)*H_ + n]);
    } else {
      int u2 = u - 2*R_*H_*H_;
      if (u2 < R_*OUT_*H_) {
        int k = u2 & 127, n = (u2>>7) & 31, r = u2 >> 12;
        W3t[u2] = f2bf(W3[(r*H_ + k)*OUT_ + n]);
      }
    }
  }
}

// ---------------- aggregation (compacted, keydesc-driven) ----------------
// One thread per (key, 32-feat quarter). Chain: kdesc (1 dwordx4) -> h.
// Empty: exit after 1 load. First edge's src/mask live in kdesc, so its
// h-load issues immediately, parallel with any further erec loads.

__global__ __launch_bounds__(256) void agg_k(
    const unsigned short* __restrict__ h_in,   // bf16 [B*N*H]
    const uint4* __restrict__ kdesc,           // {start, cnt<<20|cm, src0, m0}
    const uint2* __restrict__ erec,
    unsigned short* __restrict__ aggc){        // bf16 [1+nz][128]
  int tg = blockIdx.x*256 + threadIdx.x;       // 2,097,152
  int key = tg >> 2;
  int q   = tg & 3;
  uint4 kd = kdesc[key];
  int cnt = (int)(kd.y >> 20);
  if (cnt == 0) return;
  int cm = (int)(kd.y & 0xFFFFFu);
  int b  = key >> 17;
  const unsigned short* hb = h_in + ((size_t)b << 20);

  float fa[32];
  #pragma unroll
  for (int i=0;i<32;++i) fa[i] = 0.f;

#define UNP8(FP, V, M) do { \
  (FP)[0]+=M*bfh((V).x,0); (FP)[1]+=M*bfh((V).x,1); \
  (FP)[2]+=M*bfh((V).y,0); (FP)[3]+=M*bfh((V).y,1); \
  (FP)[4]+=M*bfh((V).z,0); (FP)[5]+=M*bfh((V).z,1); \
  (FP)[6]+=M*bfh((V).w,0); (FP)[7]+=M*bfh((V).w,1); \
} while(0)
#define MAC32(SRC, MB) do { \
  float m_ = __uint_as_float(MB); \
  const uint4* hp_ = (const uint4*)(hb + (((unsigned)(SRC))<<7) + (q<<5)); \
  uint4 v0_ = hp_[0], v1_ = hp_[1], v2_ = hp_[2], v3_ = hp_[3]; \
  UNP8(fa+0,  v0_, m_); UNP8(fa+8,  v1_, m_); \
  UNP8(fa+16, v2_, m_); UNP8(fa+24, v3_, m_); \
} while(0)

  int s = (int)kd.x;
  uint2 rc;
  if (cnt > 1) rc = erec[s+1];
  MAC32(kd.z, kd.w);
  for (int e = 1; e < cnt; ++e) {
    uint2 cur = rc;
    if (e+1 < cnt) rc = erec[s+e+1];
    MAC32(cur.x, cur.y);
  }
#undef MAC32
#undef UNP8

  unsigned short* ap = aggc + ((size_t)cm << 7) + (q<<5);
  #pragma unroll
  for (int c = 0; c < 4; ++c) {
    uint4 pk;
    pk.x = cvtpk(fa[c*8+0], fa[c*8+1]);
    pk.y = cvtpk(fa[c*8+2], fa[c*8+3]);
    pk.z = cvtpk(fa[c*8+4], fa[c*8+5]);
    pk.w = cvtpk(fa[c*8+6], fa[c*8+7]);
    *(uint4*)(ap + c*8) = pk;
  }
}

// ---------------- dense GEMM, register-direct, barrier-free ---------------
// Wave = 32x32 output tile (NOUT=128) or 16x32 (NOUT=32). A-fragments
// loaded straight from compacted aggc via cmap (16B scatter either way);
// B-frags from L2-resident Wt. Software pipeline: cmap 2 rels ahead,
// A-frags 1 rel ahead (clamped, branch-free). No LDS, no barriers.
// Block = 4 waves sharing the same A-rows (L2 reuse across col-groups).

template<int NOUT>
__global__ __launch_bounds__(256, 3) void gemm_k(
    const unsigned short* __restrict__ Agc,    // bf16 [1+nz][128]
    const int* __restrict__ cmap,              // [NKEYS]
    const unsigned short* __restrict__ Wt,     // bf16 [R][NOUT][H]
    const float* __restrict__ mobj,            // [B*N] (NOUT=32)
    unsigned short* __restrict__ h_out,        // bf16 (NOUT=128)
    float* __restrict__ out)                   // fp32 (NOUT=32)
{
  constexpr int MI = (NOUT==128) ? 2 : 1;
  const int tid = threadIdx.x, lane = tid & 63;
  const int w = tid >> 6, c16 = lane & 15, g = lane >> 4;
  const int gw = blockIdx.x*4 + w;
  int rg, cg;
  if constexpr (NOUT==128) { rg = gw >> 2; cg = gw & 3; }
  else                     { rg = gw;      cg = 0; }
  const int rbase = rg * (16*MI);
  const int ncol0 = cg * 32;

  int rows[MI];
  rows[0] = rbase + c16;
  if constexpr (MI==2) rows[1] = rbase + 16 + c16;

  f32x4 acc[MI][2];
  #pragma unroll
  for (int mi=0; mi<MI; ++mi){ acc[mi][0] = f32x4{0,0,0,0}; acc[mi][1] = f32x4{0,0,0,0}; }

  // pipeline: cm two ahead, A-frags one ahead
  int cm_c[MI], cm_n[MI];
  #pragma unroll
  for (int mi=0; mi<MI; ++mi){
    cm_c[mi] = cmap[(rows[mi]<<4) + 0];
    cm_n[mi] = cmap[(rows[mi]<<4) + 1];
  }
  short8 af_c[MI][4];
  #pragma unroll
  for (int mi=0; mi<MI; ++mi)
    #pragma unroll
    for (int kk=0; kk<4; ++kk)
      af_c[mi][kk] = *(const short8*)((const char*)Agc + ((size_t)cm_c[mi]<<8) + (kk<<6) + (g<<4));

  for (int rel = 0; rel < 16; ++rel) {
    const int rel2 = (rel+2 < 15) ? rel+2 : 15;
    int cm_t[MI];
    #pragma unroll
    for (int mi=0; mi<MI; ++mi) cm_t[mi] = cmap[(rows[mi]<<4) + rel2];

    short8 af_n[MI][4];
    #pragma unroll
    for (int mi=0; mi<MI; ++mi)
      #pragma unroll
      for (int kk=0; kk<4; ++kk)
        af_n[mi][kk] = *(const short8*)((const char*)Agc + ((size_t)cm_n[mi]<<8) + (kk<<6) + (g<<4));

    short8 bf[2][4];
    #pragma unroll
    for (int ni=0; ni<2; ++ni)
      #pragma unroll
      for (int kk=0; kk<4; ++kk)
        bf[ni][kk] = *(const short8*)(Wt + (((size_t)rel*NOUT + ncol0 + ni*16 + c16)<<7) + (kk<<5) + (g<<3));

    #pragma unroll
    for (int kk=0; kk<4; ++kk)
      #pragma unroll
      for (int mi=0; mi<MI; ++mi){
        acc[mi][0] = __builtin_amdgcn_mfma_f32_16x16x32_bf16(af_c[mi][kk], bf[0][kk], acc[mi][0], 0,0,0);
        acc[mi][1] = __builtin_amdgcn_mfma_f32_16x16x32_bf16(af_c[mi][kk], bf[1][kk], acc[mi][1], 0,0,0);
      }

    #pragma unroll
    for (int mi=0; mi<MI; ++mi){
      cm_n[mi] = cm_t[mi];
      #pragma unroll
      for (int kk=0; kk<4; ++kk) af_c[mi][kk] = af_n[mi][kk];
    }
  }

  if constexpr (NOUT == 128) {
    #pragma unroll
    for (int mi=0; mi<MI; ++mi)
      #pragma unroll
      for (int ni=0; ni<2; ++ni)
        #pragma unroll
        for (int j=0; j<4; ++j) {
          int row = rbase + mi*16 + g*4 + j;
          int col = ncol0 + ni*16 + c16;
          h_out[((size_t)row<<7) + col] = f2bf(fmaxf(acc[mi][ni][j], 0.f));
        }
  } else {
    #pragma unroll
    for (int j=0; j<4; ++j) {
      int row = rbase + g*4 + j;
      float v0 = acc[0][0][j], v1 = acc[0][1][j];
      float mx = fmaxf(v0, v1);
      #pragma unroll
      for (int s=8; s>0; s>>=1) mx = fmaxf(mx, __shfl_xor(mx, s, 16));
      float e0 = __expf(v0 - mx), e1 = __expf(v1 - mx);
      float sm = e0 + e1;
      #pragma unroll
      for (int s=8; s>0; s>>=1) sm += __shfl_xor(sm, s, 16);
      float sc = mobj[row] / sm;
      out[((size_t)row<<5) + c16]      = e0*sc;
      out[((size_t)row<<5) + 16 + c16] = e1*sc;
    }
  }
}

extern "C" void kernel_launch(void* const* d_in, const int* in_sizes, int n_in,
                              void* d_out, int out_size, void* d_ws, size_t ws_size,
                              hipStream_t stream){
  const int*   cls   = (const int*)  d_in[0];
  // d_in[1] states_objects: unused by reference
  const int*   et    = (const int*)  d_in[2];
  const int*   ec    = (const int*)  d_in[3];
  const float* mobj  = (const float*)d_in[4];
  const float* medge = (const float*)d_in[5];
  const float* emb   = (const float*)d_in[6];
  const float* W1    = (const float*)d_in[7];
  const float* W2    = (const float*)d_in[8];
  const float* W3    = (const float*)d_in[9];
  float* out = (float*)d_out;

  char* ws = (char*)d_ws;
  size_t o = 0;
  auto alloc = [&](size_t bytes)->char*{
    char* p = ws + o;
    o += (bytes + 255) & ~(size_t)255;
    return p;
  };
  unsigned short* hA    = (unsigned short*)alloc((size_t)B_*N_*H_*2);
  unsigned short* hB    = (unsigned short*)alloc((size_t)B_*N_*H_*2);
  unsigned short* W1t   = (unsigned short*)alloc((size_t)R_*H_*H_*2);
  unsigned short* W2t   = (unsigned short*)alloc((size_t)R_*H_*H_*2);
  unsigned short* W3t   = (unsigned short*)alloc((size_t)R_*OUT_*H_*2);
  int*            cnt   = (int*)alloc((size_t)NKEYS*4);
  int*            off   = (int*)alloc((size_t)NKEYS*4);
  int*            offp  = (int*)alloc((size_t)NKEYS*4);
  int*            cidxp = (int*)alloc((size_t)NKEYS*4);
  int*            cmap  = (int*)alloc((size_t)NKEYS*4);
  int*            bsumV = (int*)alloc(512*4);
  int*            bsumF = (int*)alloc(512*4);
  uint4*          kdesc = (uint4*)alloc((size_t)NKEYS*16);
  uint2*          erec  = (uint2*)alloc((size_t)NEDGE*8);
  unsigned short* aggc  = (unsigned short*)alloc(((size_t)NKEYS+1)*H_*2);  // 128 MB
  (void)ws_size; (void)in_sizes; (void)n_in; (void)out_size;

  // CSR build + compaction + keydesc
  hipMemsetAsync(cnt, 0, (size_t)NKEYS*4, stream);
  hipLaunchKernelGGL(hist_k,  dim3(NEDGE/256), dim3(256), 0, stream, et, ec, cnt);
  hipLaunchKernelGGL(scanA_k, dim3(512), dim3(256), 0, stream, cnt, offp, cidxp, bsumV, bsumF);
  hipLaunchKernelGGL(scanB_k, dim3(2),   dim3(256), 0, stream, bsumV, bsumF);
  hipLaunchKernelGGL(scanC_k, dim3(512), dim3(256), 0, stream, offp, cidxp, bsumV, bsumF,
                     cnt, off, cmap, kdesc);
  hipLaunchKernelGGL(fill_k,  dim3(NEDGE/256), dim3(256), 0, stream, et, ec, medge, off, erec, kdesc);

  // h0 = bf16(embed[class]);  W -> bf16 [r][n][k];  zero slot 0 of aggc
  hipLaunchKernelGGL(prep_k, dim3((B_*N_*32 + 2*R_*H_*H_ + R_*OUT_*H_)/256), dim3(256), 0, stream,
                     cls, emb, W1, W2, W3, hA, W1t, W2t, W3t, aggc);

  const int aggGrid = (NKEYS*4)/256;            // 8192
  const int g128    = (B_*N_/32)*4/4;           // 4096 waves / 4 = 1024 blocks
  const int g32     = (B_*N_/16)/4;             // 2048 waves / 4 = 512 blocks

  // layer 1
  hipLaunchKernelGGL(agg_k, dim3(aggGrid), dim3(256), 0, stream, hA, kdesc, erec, aggc);
  hipLaunchKernelGGL((gemm_k<128>), dim3(g128), dim3(256), 0, stream,
                     aggc, cmap, W1t, (const float*)nullptr, hB, (float*)nullptr);
  // layer 2
  hipLaunchKernelGGL(agg_k, dim3(aggGrid), dim3(256), 0, stream, hB, kdesc, erec, aggc);
  hipLaunchKernelGGL((gemm_k<128>), dim3(g128), dim3(256), 0, stream,
                     aggc, cmap, W2t, (const float*)nullptr, hA, (float*)nullptr);
  // layer 3 (+ fused softmax * mask)
  hipLaunchKernelGGL(agg_k, dim3(aggGrid), dim3(256), 0, stream, hA, kdesc, erec, aggc);
  hipLaunchKernelGGL((gemm_k<32>), dim3(g32), dim3(256), 0, stream,
                     aggc, cmap, W3t, mobj, (unsigned short*)nullptr, out);
}

// Round 10
// 269.179 us; speedup vs baseline: 1.6772x; 1.6772x over previous
//
#include <hip/hip_runtime.h>

typedef __attribute__((ext_vector_type(4))) float f32x4;
typedef __attribute__((ext_vector_type(8))) short short8;

#define B_ 4
#define N_ 8192
#define E_ 131072
#define R_ 16
#define H_ 128
#define OUT_ 32
#define NKEYS (B_*N_*R_)   /* 524288 */
#define NEDGE (B_*E_)      /* 524288 */

__device__ __forceinline__ unsigned short f2bf(float f){
  unsigned int u = __float_as_uint(f);
  u = (u + 0x7fffu + ((u>>16)&1u)) >> 16;
  return (unsigned short)u;
}
__device__ __forceinline__ float bfh(unsigned u, int hi){
  return __uint_as_float(hi ? (u & 0xffff0000u) : (u << 16));
}
__device__ __forceinline__ unsigned cvtpk(float lo, float hi){
  unsigned r;
  asm("v_cvt_pk_bf16_f32 %0, %1, %2" : "=v"(r) : "v"(lo), "v"(hi));
  return r;
}
__device__ __forceinline__ void glds16(const void* g, void* l){
  __builtin_amdgcn_global_load_lds((const __attribute__((address_space(1))) unsigned int*)g,
                                   (__attribute__((address_space(3))) unsigned int*)l,
                                   16, 0, 0);
}

// ---------------- CSR build: key = node*16 + rel, node = b*8192+dst -------

__global__ void hist_k(const int* __restrict__ et, const int* __restrict__ ec,
                       int* __restrict__ cnt){
  int e = blockIdx.x*256 + threadIdx.x;
  int b = e >> 17;                  // E = 2^17
  int dst = et[2*e+1];
  int r  = ec[e];
  atomicAdd(&cnt[(((b<<13)+dst)<<4) + r], 1);
}

// pass A: per-block exclusive scans of cnt values AND of (cnt!=0) flags
__global__ void scanA_k(const int* __restrict__ cnt,
                        int* __restrict__ offp, int* __restrict__ cidxp,
                        int* __restrict__ bsumV, int* __restrict__ bsumF){
  __shared__ int ldsV[256], ldsF[256];
  int t = threadIdx.x;
  int base = blockIdx.x*1024 + t*4;
  int4 v = *(const int4*)(cnt + base);
  int4 f; f.x = v.x!=0; f.y = v.y!=0; f.z = v.z!=0; f.w = v.w!=0;
  ldsV[t] = v.x+v.y+v.z+v.w;
  ldsF[t] = f.x+f.y+f.z+f.w;
  __syncthreads();
  for (int off=1; off<256; off<<=1){
    int xv = (t>=off) ? ldsV[t-off] : 0;
    int xf = (t>=off) ? ldsF[t-off] : 0;
    __syncthreads();
    ldsV[t] += xv; ldsF[t] += xf;
    __syncthreads();
  }
  if (t==255){ bsumV[blockIdx.x] = ldsV[255]; bsumF[blockIdx.x] = ldsF[255]; }
  int pv = (t==0) ? 0 : ldsV[t-1];
  int pf = (t==0) ? 0 : ldsF[t-1];
  int4 ov; ov.x = pv; ov.y = ov.x+v.x; ov.z = ov.y+v.y; ov.w = ov.z+v.z;
  int4 of; of.x = pf; of.y = of.x+f.x; of.z = of.y+f.y; of.w = of.z+f.z;
  *(int4*)(offp  + base) = ov;
  *(int4*)(cidxp + base) = of;
}

// pass B: single-block scan of one 512-entry bsum array (grid=2: V then F)
__global__ void scanB_k(int* __restrict__ bsumV, int* __restrict__ bsumF){
  int* bs = blockIdx.x ? bsumF : bsumV;
  __shared__ int lds[256];
  int t = threadIdx.x;
  int2 v = *(const int2*)(bs + t*2);
  lds[t] = v.x+v.y;
  __syncthreads();
  for (int off=1; off<256; off<<=1){
    int x = (t>=off) ? lds[t-off] : 0;
    __syncthreads();
    lds[t] += x;
    __syncthreads();
  }
  int pre = (t==0) ? 0 : lds[t-1];
  int2 o; o.x = pre; o.y = pre + v.x;
  *(int2*)(bs + t*2) = o;
}

// pass C: finalize off (starts), cmap, and keydesc.xy = {start, cnt<<20|cm}
__global__ void scanC_k(const int* __restrict__ offp, const int* __restrict__ cidxp,
                        const int* __restrict__ bsumV, const int* __restrict__ bsumF,
                        const int* __restrict__ cnt,
                        int* __restrict__ off, int* __restrict__ cmap,
                        uint4* __restrict__ kdesc){
  int t = threadIdx.x;
  int base = blockIdx.x*1024 + t*4;
  int addV = bsumV[blockIdx.x];
  int addF = bsumF[blockIdx.x] + 1;      // +1: slot 0 is the zero block
  int4 o  = *(const int4*)(offp + base);
  o.x+=addV; o.y+=addV; o.z+=addV; o.w+=addV;
  *(int4*)(off + base) = o;
  int4 cx = *(const int4*)(cidxp + base);
  int4 cv = *(const int4*)(cnt + base);
  int4 cm;
  cm.x = cv.x ? cx.x+addF : 0;
  cm.y = cv.y ? cx.y+addF : 0;
  cm.z = cv.z ? cx.z+addF : 0;
  cm.w = cv.w ? cx.w+addF : 0;
  *(int4*)(cmap + base) = cm;
  *(int2*)&kdesc[base+0].x = make_int2(o.x, (cv.x<<20)|cm.x);
  *(int2*)&kdesc[base+1].x = make_int2(o.y, (cv.y<<20)|cm.y);
  *(int2*)&kdesc[base+2].x = make_int2(o.z, (cv.z<<20)|cm.z);
  *(int2*)&kdesc[base+3].x = make_int2(o.w, (cv.w<<20)|cm.w);
}

// fill consumes off (start -> end) via atomicAdd; first edge also lands in
// keydesc.zw = {src0, mask0}.
__global__ void fill_k(const int* __restrict__ et, const int* __restrict__ ec,
                       const float* __restrict__ me, int* __restrict__ off,
                       uint2* __restrict__ erec, uint4* __restrict__ kdesc){
  int e = blockIdx.x*256 + threadIdx.x;
  int b = e >> 17;
  int src = et[2*e];
  int dst = et[2*e+1];
  int r  = ec[e];
  int key = (((b<<13)+dst)<<4) + r;
  unsigned mbits = __float_as_uint(me[e]);
  int pos = atomicAdd(&off[key], 1);
  erec[pos] = make_uint2((unsigned)src, mbits);
  int start = (int)kdesc[key].x;
  if (pos == start)
    *(uint2*)&kdesc[key].z = make_uint2((unsigned)src, mbits);
}

// ---------------- feature prep (embed + 3x W-transpose + zero slot) -------

__global__ void prep_k(const int* __restrict__ cls, const float* __restrict__ emb,
                       const float* __restrict__ W1, const float* __restrict__ W2,
                       const float* __restrict__ W3,
                       unsigned short* __restrict__ h,
                       unsigned short* __restrict__ W1t,
                       unsigned short* __restrict__ W2t,
                       unsigned short* __restrict__ W3t,
                       unsigned short* __restrict__ aggc){
  int t = blockIdx.x*256 + threadIdx.x;
  if (blockIdx.x == 0 && threadIdx.x < 16) {
    *(uint4*)((char*)aggc + threadIdx.x*16) = make_uint4(0,0,0,0);  // zero slot
  }
  if (t < B_*N_*32) {
    int node = t>>5, c = t&31;
    int cl = cls[node];
    float4 v = *(const float4*)(emb + cl*H_ + c*4);
    uint2 o;
    o.x = f2bf(v.x) | ((unsigned int)f2bf(v.y)<<16);
    o.y = f2bf(v.z) | ((unsigned int)f2bf(v.w)<<16);
    *(uint2*)(h + node*H_ + c*4) = o;
  } else {
    int u = t - B_*N_*32;
    if (u < R_*H_*H_) {
      int k = u & 127, n = (u>>7) & 127, r = u >> 14;
      W1t[u] = f2bf(W1[(r*H_ + k)*H_ + n]);
    } else if (u < 2*R_*H_*H_) {
      int u2 = u - R_*H_*H_;
      int k = u2 & 127, n = (u2>>7) & 127, r = u2 >> 14;
      W2t[u2] = f2bf(W2[(r*H_ + k)*H_ + n]);
    } else {
      int u2 = u - 2*R_*H_*H_;
      if (u2 < R_*OUT_*H_) {
        int k = u2 & 127, n = (u2>>7) & 31, r = u2 >> 12;
        W3t[u2] = f2bf(W3[(r*H_ + k)*OUT_ + n]);
      }
    }
  }
}

// ---------------- aggregation (compacted, keydesc-driven) ----------------

__global__ __launch_bounds__(256) void agg_k(
    const unsigned short* __restrict__ h_in,   // bf16 [B*N*H]
    const uint4* __restrict__ kdesc,           // {start, cnt<<20|cm, src0, m0}
    const uint2* __restrict__ erec,
    unsigned short* __restrict__ aggc){        // bf16 [1+nz][128]
  int tg = blockIdx.x*256 + threadIdx.x;       // 2,097,152
  int key = tg >> 2;
  int q   = tg & 3;
  uint4 kd = kdesc[key];
  int cnt = (int)(kd.y >> 20);
  if (cnt == 0) return;
  int cm = (int)(kd.y & 0xFFFFFu);
  int b  = key >> 17;
  const unsigned short* hb = h_in + ((size_t)b << 20);

  float fa[32];
  #pragma unroll
  for (int i=0;i<32;++i) fa[i] = 0.f;

#define UNP8(FP, V, M) do { \
  (FP)[0]+=M*bfh((V).x,0); (FP)[1]+=M*bfh((V).x,1); \
  (FP)[2]+=M*bfh((V).y,0); (FP)[3]+=M*bfh((V).y,1); \
  (FP)[4]+=M*bfh((V).z,0); (FP)[5]+=M*bfh((V).z,1); \
  (FP)[6]+=M*bfh((V).w,0); (FP)[7]+=M*bfh((V).w,1); \
} while(0)
#define MAC32(SRC, MB) do { \
  float m_ = __uint_as_float(MB); \
  const uint4* hp_ = (const uint4*)(hb + (((unsigned)(SRC))<<7) + (q<<5)); \
  uint4 v0_ = hp_[0], v1_ = hp_[1], v2_ = hp_[2], v3_ = hp_[3]; \
  UNP8(fa+0,  v0_, m_); UNP8(fa+8,  v1_, m_); \
  UNP8(fa+16, v2_, m_); UNP8(fa+24, v3_, m_); \
} while(0)

  int s = (int)kd.x;
  uint2 rc;
  if (cnt > 1) rc = erec[s+1];
  MAC32(kd.z, kd.w);
  for (int e = 1; e < cnt; ++e) {
    uint2 cur = rc;
    if (e+1 < cnt) rc = erec[s+e+1];
    MAC32(cur.x, cur.y);
  }
#undef MAC32
#undef UNP8

  unsigned short* ap = aggc + ((size_t)cm << 7) + (q<<5);
  #pragma unroll
  for (int c = 0; c < 4; ++c) {
    uint4 pk;
    pk.x = cvtpk(fa[c*8+0], fa[c*8+1]);
    pk.y = cvtpk(fa[c*8+2], fa[c*8+3]);
    pk.z = cvtpk(fa[c*8+4], fa[c*8+5]);
    pk.w = cvtpk(fa[c*8+6], fa[c*8+7]);
    *(uint4*)(ap + c*8) = pk;
  }
}

// ---------------- dense GEMM over compacted A (LDS, 3-deep pipeline) ------
// NOUT=128: M-tile 64, grid 512 (2 blocks/CU). NOUT=32: M-tile 128, grid
// 256 (+fused softmax). 3 LDS buffers; STAGE(k+2) issued per iter; counted
// vmcnt (never 0 in main loop) keeps 2 stages in flight across barriers.
// A staged via cmap indirection (empty rows -> zero slot), pre-swizzled
// global source so ds_read_b128 is conflict-free (rule 21 / m97 pattern).

template<int NOUT>
__global__ __launch_bounds__(512, 4) void gemm_k(
    const unsigned short* __restrict__ Agc,    // bf16 [1+nz][128]
    const int* __restrict__ cmap,              // [NKEYS]
    const unsigned short* __restrict__ Wt,     // bf16 [R][NOUT][H]
    const float* __restrict__ mobj,            // [B*N] (NOUT=32)
    unsigned short* __restrict__ h_out,        // bf16 (NOUT=128)
    float* __restrict__ out)                   // fp32 (NOUT=32)
{
  constexpr int MT  = (NOUT==128) ? 64 : 128;
  constexpr int MI  = (NOUT==128) ? 2 : 1;
  constexpr int NIw = 2;
  __shared__ __align__(16) unsigned short A_s[3][MT*64];    // 3 x 8/16 KB
  __shared__ __align__(16) unsigned short B_s[3][NOUT*64];  // 3 x 16/4 KB
  __shared__ int cmap_s[MT*16];                             // 4/8 KB

  const int tid  = threadIdx.x;
  const int lane = tid & 63;
  const int w    = tid >> 6;
  const int c16  = lane & 15;
  const int g    = lane >> 4;
  const int m0   = blockIdx.x * MT;
  const int mbase = (NOUT==128) ? ((w>>2)<<5) : (w<<4);
  const int nbase = (NOUT==128) ? ((w&3)<<5) : 0;

  // prologue: this tile's cmap entries -> LDS
  if constexpr (NOUT==128) {
    *(int2*)&cmap_s[tid<<1] = *(const int2*)(cmap + m0*16 + (tid<<1));
  } else {
    *(int4*)&cmap_s[tid<<2] = *(const int4*)(cmap + m0*16 + (tid<<2));
  }
  __syncthreads();

#define STAGE(KC, BUF) do { \
  const int kc_ = (KC); \
  if constexpr (NOUT==128) { \
    int uid_ = (w<<6) + lane; \
    int m_ = uid_>>3, u_ = uid_&7; \
    int cm_ = cmap_s[(m_<<4) + (kc_>>1)]; \
    glds16((const char*)Agc + ((size_t)cm_<<8) + ((kc_&1)<<7) + ((u_ ^ (m_&7))<<4), \
           &A_s[BUF][uid_<<3]); \
    _Pragma("unroll") \
    for (int i_=0;i_<2;++i_){ \
      int uid2_ = ((w*2+i_)<<6) + lane; \
      int n_ = uid2_>>3, u2_ = uid2_&7; \
      glds16((const char*)Wt + ((size_t)((kc_>>1)*128 + n_)<<8) + ((kc_&1)<<7) + ((u2_ ^ (n_&7))<<4), \
             &B_s[BUF][uid2_<<3]); } \
  } else { \
    _Pragma("unroll") \
    for (int i_=0;i_<2;++i_){ \
      int uid_ = ((w*2+i_)<<6) + lane; \
      int m_ = uid_>>3, u_ = uid_&7; \
      int cm_ = cmap_s[(m_<<4) + (kc_>>1)]; \
      glds16((const char*)Agc + ((size_t)cm_<<8) + ((kc_&1)<<7) + ((u_ ^ (m_&7))<<4), \
             &A_s[BUF][uid_<<3]); } \
    if (w < 4) { \
      int uid_ = (w<<6) + lane; \
      int n_ = uid_>>3, u_ = uid_&7; \
      glds16((const char*)Wt + ((size_t)((kc_>>1)*32 + n_)<<8) + ((kc_&1)<<7) + ((u_ ^ (n_&7))<<4), \
             &B_s[BUF][uid_<<3]); } \
  } \
} while(0)

// per-wave loads/stage: NOUT=128 -> 3 (uniform); NOUT=32 -> w<4:3, else 2.
#define WAIT_MAIN do { \
  if constexpr (NOUT==128) { asm volatile("s_waitcnt vmcnt(6)" ::: "memory"); } \
  else { if (w < 4) asm volatile("s_waitcnt vmcnt(6)" ::: "memory"); \
         else       asm volatile("s_waitcnt vmcnt(4)" ::: "memory"); } \
} while(0)
#define WAIT_T1 do { \
  if constexpr (NOUT==128) { asm volatile("s_waitcnt vmcnt(3)" ::: "memory"); } \
  else { if (w < 4) asm volatile("s_waitcnt vmcnt(3)" ::: "memory"); \
         else       asm volatile("s_waitcnt vmcnt(2)" ::: "memory"); } \
} while(0)

  f32x4 acc[MI][NIw];
  #pragma unroll
  for (int mi=0; mi<MI; ++mi)
    #pragma unroll
    for (int ni=0; ni<NIw; ++ni)
      acc[mi][ni] = f32x4{0.f,0.f,0.f,0.f};

#define COMPUTE(BUF) do { \
  _Pragma("unroll") \
  for (int kk=0; kk<2; ++kk) { \
    short8 af[MI], bfr[NIw]; \
    _Pragma("unroll") \
    for (int mi=0; mi<MI; ++mi) { \
      int m_ = mbase + mi*16 + c16; \
      af[mi] = *(const short8*)((const char*)&A_s[BUF][0] + m_*128 \
               + (((kk<<6) + (g<<4)) ^ ((m_&7)<<4))); } \
    _Pragma("unroll") \
    for (int ni=0; ni<NIw; ++ni) { \
      int n_ = nbase + ni*16 + c16; \
      bfr[ni] = *(const short8*)((const char*)&B_s[BUF][0] + n_*128 \
               + (((kk<<6) + (g<<4)) ^ ((n_&7)<<4))); } \
    _Pragma("unroll") \
    for (int mi=0; mi<MI; ++mi) \
      _Pragma("unroll") \
      for (int ni=0; ni<NIw; ++ni) \
        acc[mi][ni] = __builtin_amdgcn_mfma_f32_16x16x32_bf16(af[mi], bfr[ni], acc[mi][ni], 0,0,0); \
  } \
} while(0)

  STAGE(0, 0);
  STAGE(1, 1);
  for (int kc = 0; kc < 30; ++kc) {
    STAGE(kc+2, (kc+2)%3);
    WAIT_MAIN;
    __builtin_amdgcn_s_barrier();
    COMPUTE(kc%3);
    asm volatile("s_waitcnt lgkmcnt(0)" ::: "memory");
    __builtin_amdgcn_s_barrier();
  }
  // kc = 30
  WAIT_T1;
  __builtin_amdgcn_s_barrier();
  COMPUTE(0);
  asm volatile("s_waitcnt lgkmcnt(0)" ::: "memory");
  __builtin_amdgcn_s_barrier();
  // kc = 31
  asm volatile("s_waitcnt vmcnt(0)" ::: "memory");
  __builtin_amdgcn_s_barrier();
  COMPUTE(1);

  if constexpr (NOUT == 128) {
    #pragma unroll
    for (int mi=0; mi<MI; ++mi)
      #pragma unroll
      for (int ni=0; ni<NIw; ++ni)
        #pragma unroll
        for (int j=0; j<4; ++j) {
          int row = mbase + mi*16 + (g<<2) + j;
          int col = nbase + ni*16 + c16;
          h_out[((size_t)(m0+row)<<7) + col] = f2bf(fmaxf(acc[mi][ni][j], 0.f));
        }
  } else {
    #pragma unroll
    for (int j=0; j<4; ++j) {
      int row = mbase + (g<<2) + j;
      float v0 = acc[0][0][j], v1 = acc[0][1][j];
      float mx = fmaxf(v0, v1);
      #pragma unroll
      for (int s=8; s>0; s>>=1) mx = fmaxf(mx, __shfl_xor(mx, s, 16));
      float e0 = __expf(v0 - mx), e1 = __expf(v1 - mx);
      float sm = e0 + e1;
      #pragma unroll
      for (int s=8; s>0; s>>=1) sm += __shfl_xor(sm, s, 16);
      float sc = mobj[m0+row] / sm;
      out[((size_t)(m0+row)<<5) + c16]      = e0*sc;
      out[((size_t)(m0+row)<<5) + 16 + c16] = e1*sc;
    }
  }
#undef STAGE
#undef WAIT_MAIN
#undef WAIT_T1
#undef COMPUTE
}

extern "C" void kernel_launch(void* const* d_in, const int* in_sizes, int n_in,
                              void* d_out, int out_size, void* d_ws, size_t ws_size,
                              hipStream_t stream){
  const int*   cls   = (const int*)  d_in[0];
  // d_in[1] states_objects: unused by reference
  const int*   et    = (const int*)  d_in[2];
  const int*   ec    = (const int*)  d_in[3];
  const float* mobj  = (const float*)d_in[4];
  const float* medge = (const float*)d_in[5];
  const float* emb   = (const float*)d_in[6];
  const float* W1    = (const float*)d_in[7];
  const float* W2    = (const float*)d_in[8];
  const float* W3    = (const float*)d_in[9];
  float* out = (float*)d_out;

  char* ws = (char*)d_ws;
  size_t o = 0;
  auto alloc = [&](size_t bytes)->char*{
    char* p = ws + o;
    o += (bytes + 255) & ~(size_t)255;
    return p;
  };
  unsigned short* hA    = (unsigned short*)alloc((size_t)B_*N_*H_*2);
  unsigned short* hB    = (unsigned short*)alloc((size_t)B_*N_*H_*2);
  unsigned short* W1t   = (unsigned short*)alloc((size_t)R_*H_*H_*2);
  unsigned short* W2t   = (unsigned short*)alloc((size_t)R_*H_*H_*2);
  unsigned short* W3t   = (unsigned short*)alloc((size_t)R_*OUT_*H_*2);
  int*            cnt   = (int*)alloc((size_t)NKEYS*4);
  int*            off   = (int*)alloc((size_t)NKEYS*4);
  int*            offp  = (int*)alloc((size_t)NKEYS*4);
  int*            cidxp = (int*)alloc((size_t)NKEYS*4);
  int*            cmap  = (int*)alloc((size_t)NKEYS*4);
  int*            bsumV = (int*)alloc(512*4);
  int*            bsumF = (int*)alloc(512*4);
  uint4*          kdesc = (uint4*)alloc((size_t)NKEYS*16);
  uint2*          erec  = (uint2*)alloc((size_t)NEDGE*8);
  unsigned short* aggc  = (unsigned short*)alloc(((size_t)NKEYS+1)*H_*2);  // 128 MB
  (void)ws_size; (void)in_sizes; (void)n_in; (void)out_size;

  // CSR build + compaction + keydesc
  hipMemsetAsync(cnt, 0, (size_t)NKEYS*4, stream);
  hipLaunchKernelGGL(hist_k,  dim3(NEDGE/256), dim3(256), 0, stream, et, ec, cnt);
  hipLaunchKernelGGL(scanA_k, dim3(512), dim3(256), 0, stream, cnt, offp, cidxp, bsumV, bsumF);
  hipLaunchKernelGGL(scanB_k, dim3(2),   dim3(256), 0, stream, bsumV, bsumF);
  hipLaunchKernelGGL(scanC_k, dim3(512), dim3(256), 0, stream, offp, cidxp, bsumV, bsumF,
                     cnt, off, cmap, kdesc);
  hipLaunchKernelGGL(fill_k,  dim3(NEDGE/256), dim3(256), 0, stream, et, ec, medge, off, erec, kdesc);

  // h0 = bf16(embed[class]);  W -> bf16 [r][n][k];  zero slot 0 of aggc
  hipLaunchKernelGGL(prep_k, dim3((B_*N_*32 + 2*R_*H_*H_ + R_*OUT_*H_)/256), dim3(256), 0, stream,
                     cls, emb, W1, W2, W3, hA, W1t, W2t, W3t, aggc);

  const int aggGrid = (NKEYS*4)/256;   // 8192
  const int g128    = (B_*N_)/64;      // 512 blocks (2/CU)
  const int g32     = (B_*N_)/128;     // 256 blocks

  // layer 1
  hipLaunchKernelGGL(agg_k, dim3(aggGrid), dim3(256), 0, stream, hA, kdesc, erec, aggc);
  hipLaunchKernelGGL((gemm_k<128>), dim3(g128), dim3(512), 0, stream,
                     aggc, cmap, W1t, (const float*)nullptr, hB, (float*)nullptr);
  // layer 2
  hipLaunchKernelGGL(agg_k, dim3(aggGrid), dim3(256), 0, stream, hB, kdesc, erec, aggc);
  hipLaunchKernelGGL((gemm_k<128>), dim3(g128), dim3(512), 0, stream,
                     aggc, cmap, W2t, (const float*)nullptr, hA, (float*)nullptr);
  // layer 3 (+ fused softmax * mask)
  hipLaunchKernelGGL(agg_k, dim3(aggGrid), dim3(256), 0, stream, hA, kdesc, erec, aggc);
  hipLaunchKernelGGL((gemm_k<32>), dim3(g32), dim3(512), 0, stream,
                     aggc, cmap, W3t, mobj, (unsigned short*)nullptr, out);
}

// Round 11
// 266.324 us; speedup vs baseline: 1.6952x; 1.0107x over previous
//
#include <hip/hip_runtime.h>

typedef __attribute__((ext_vector_type(4))) float f32x4;
typedef __attribute__((ext_vector_type(8))) short short8;

#define B_ 4
#define N_ 8192
#define E_ 131072
#define R_ 16
#define H_ 128
#define OUT_ 32
#define NKEYS (B_*N_*R_)   /* 524288 */
#define NEDGE (B_*E_)      /* 524288 */

__device__ __forceinline__ unsigned short f2bf(float f){
  unsigned int u = __float_as_uint(f);
  u = (u + 0x7fffu + ((u>>16)&1u)) >> 16;
  return (unsigned short)u;
}
__device__ __forceinline__ float bfh(unsigned u, int hi){
  return __uint_as_float(hi ? (u & 0xffff0000u) : (u << 16));
}
__device__ __forceinline__ unsigned cvtpk(float lo, float hi){
  unsigned r;
  asm("v_cvt_pk_bf16_f32 %0, %1, %2" : "=v"(r) : "v"(lo), "v"(hi));
  return r;
}
__device__ __forceinline__ void glds16(const void* g, void* l){
  __builtin_amdgcn_global_load_lds((const __attribute__((address_space(1))) unsigned int*)g,
                                   (__attribute__((address_space(3))) unsigned int*)l,
                                   16, 0, 0);
}

// ---------------- CSR build: key = node*16 + rel, node = b*8192+dst -------

__global__ void hist_k(const int* __restrict__ et, const int* __restrict__ ec,
                       int* __restrict__ cnt){
  int e = blockIdx.x*256 + threadIdx.x;
  int b = e >> 17;                  // E = 2^17
  int dst = et[2*e+1];
  int r  = ec[e];
  atomicAdd(&cnt[(((b<<13)+dst)<<4) + r], 1);
}

// pass A: per-block exclusive scans of cnt values AND of (cnt!=0) flags
__global__ void scanA_k(const int* __restrict__ cnt,
                        int* __restrict__ offp, int* __restrict__ cidxp,
                        int* __restrict__ bsumV, int* __restrict__ bsumF){
  __shared__ int ldsV[256], ldsF[256];
  int t = threadIdx.x;
  int base = blockIdx.x*1024 + t*4;
  int4 v = *(const int4*)(cnt + base);
  int4 f; f.x = v.x!=0; f.y = v.y!=0; f.z = v.z!=0; f.w = v.w!=0;
  ldsV[t] = v.x+v.y+v.z+v.w;
  ldsF[t] = f.x+f.y+f.z+f.w;
  __syncthreads();
  for (int off=1; off<256; off<<=1){
    int xv = (t>=off) ? ldsV[t-off] : 0;
    int xf = (t>=off) ? ldsF[t-off] : 0;
    __syncthreads();
    ldsV[t] += xv; ldsF[t] += xf;
    __syncthreads();
  }
  if (t==255){ bsumV[blockIdx.x] = ldsV[255]; bsumF[blockIdx.x] = ldsF[255]; }
  int pv = (t==0) ? 0 : ldsV[t-1];
  int pf = (t==0) ? 0 : ldsF[t-1];
  int4 ov; ov.x = pv; ov.y = ov.x+v.x; ov.z = ov.y+v.y; ov.w = ov.z+v.z;
  int4 of; of.x = pf; of.y = of.x+f.x; of.z = of.y+f.y; of.w = of.z+f.z;
  *(int4*)(offp  + base) = ov;
  *(int4*)(cidxp + base) = of;
}

// pass B: single-block scan of one 512-entry bsum array (grid=2: V then F)
__global__ void scanB_k(int* __restrict__ bsumV, int* __restrict__ bsumF){
  int* bs = blockIdx.x ? bsumF : bsumV;
  __shared__ int lds[256];
  int t = threadIdx.x;
  int2 v = *(const int2*)(bs + t*2);
  lds[t] = v.x+v.y;
  __syncthreads();
  for (int off=1; off<256; off<<=1){
    int x = (t>=off) ? lds[t-off] : 0;
    __syncthreads();
    lds[t] += x;
    __syncthreads();
  }
  int pre = (t==0) ? 0 : lds[t-1];
  int2 o; o.x = pre; o.y = pre + v.x;
  *(int2*)(bs + t*2) = o;
}

// pass C: finalize off (starts), cmap, and keydesc.xy = {start, cnt<<20|cm}
__global__ void scanC_k(const int* __restrict__ offp, const int* __restrict__ cidxp,
                        const int* __restrict__ bsumV, const int* __restrict__ bsumF,
                        const int* __restrict__ cnt,
                        int* __restrict__ off, int* __restrict__ cmap,
                        uint4* __restrict__ kdesc){
  int t = threadIdx.x;
  int base = blockIdx.x*1024 + t*4;
  int addV = bsumV[blockIdx.x];
  int addF = bsumF[blockIdx.x] + 1;      // +1: slot 0 is the zero block
  int4 o  = *(const int4*)(offp + base);
  o.x+=addV; o.y+=addV; o.z+=addV; o.w+=addV;
  *(int4*)(off + base) = o;
  int4 cx = *(const int4*)(cidxp + base);
  int4 cv = *(const int4*)(cnt + base);
  int4 cm;
  cm.x = cv.x ? cx.x+addF : 0;
  cm.y = cv.y ? cx.y+addF : 0;
  cm.z = cv.z ? cx.z+addF : 0;
  cm.w = cv.w ? cx.w+addF : 0;
  *(int4*)(cmap + base) = cm;
  *(int2*)&kdesc[base+0].x = make_int2(o.x, (cv.x<<20)|cm.x);
  *(int2*)&kdesc[base+1].x = make_int2(o.y, (cv.y<<20)|cm.y);
  *(int2*)&kdesc[base+2].x = make_int2(o.z, (cv.z<<20)|cm.z);
  *(int2*)&kdesc[base+3].x = make_int2(o.w, (cv.w<<20)|cm.w);
}

// fill consumes off (start -> end) via atomicAdd; first edge also lands in
// keydesc.zw = {src0, mask0}.
__global__ void fill_k(const int* __restrict__ et, const int* __restrict__ ec,
                       const float* __restrict__ me, int* __restrict__ off,
                       uint2* __restrict__ erec, uint4* __restrict__ kdesc){
  int e = blockIdx.x*256 + threadIdx.x;
  int b = e >> 17;
  int src = et[2*e];
  int dst = et[2*e+1];
  int r  = ec[e];
  int key = (((b<<13)+dst)<<4) + r;
  unsigned mbits = __float_as_uint(me[e]);
  int pos = atomicAdd(&off[key], 1);
  erec[pos] = make_uint2((unsigned)src, mbits);
  int start = (int)kdesc[key].x;
  if (pos == start)
    *(uint2*)&kdesc[key].z = make_uint2((unsigned)src, mbits);
}

// ---------------- feature prep (embed + 3x W-transpose + zero slot) -------

__global__ void prep_k(const int* __restrict__ cls, const float* __restrict__ emb,
                       const float* __restrict__ W1, const float* __restrict__ W2,
                       const float* __restrict__ W3,
                       unsigned short* __restrict__ h,
                       unsigned short* __restrict__ W1t,
                       unsigned short* __restrict__ W2t,
                       unsigned short* __restrict__ W3t,
                       unsigned short* __restrict__ aggc){
  int t = blockIdx.x*256 + threadIdx.x;
  if (blockIdx.x == 0 && threadIdx.x < 16) {
    *(uint4*)((char*)aggc + threadIdx.x*16) = make_uint4(0,0,0,0);  // zero slot
  }
  if (t < B_*N_*32) {
    int node = t>>5, c = t&31;
    int cl = cls[node];
    float4 v = *(const float4*)(emb + cl*H_ + c*4);
    uint2 o;
    o.x = f2bf(v.x) | ((unsigned int)f2bf(v.y)<<16);
    o.y = f2bf(v.z) | ((unsigned int)f2bf(v.w)<<16);
    *(uint2*)(h + node*H_ + c*4) = o;
  } else {
    int u = t - B_*N_*32;
    if (u < R_*H_*H_) {
      int k = u & 127, n = (u>>7) & 127, r = u >> 14;
      W1t[u] = f2bf(W1[(r*H_ + k)*H_ + n]);
    } else if (u < 2*R_*H_*H_) {
      int u2 = u - R_*H_*H_;
      int k = u2 & 127, n = (u2>>7) & 127, r = u2 >> 14;
      W2t[u2] = f2bf(W2[(r*H_ + k)*H_ + n]);
    } else {
      int u2 = u - 2*R_*H_*H_;
      if (u2 < R_*OUT_*H_) {
        int k = u2 & 127, n = (u2>>7) & 31, r = u2 >> 12;
        W3t[u2] = f2bf(W3[(r*H_ + k)*OUT_ + n]);
      }
    }
  }
}

// ---------------- aggregation (compacted, keydesc, XCD-batch affine) ------
// XCD x = blk&7 serves batch x>>1 only -> per-XCD h slice = 2MB < 4MB L2,
// so all h gathers are L2 hits. Bijective remap over 8192 blocks.

__global__ __launch_bounds__(256) void agg_k(
    const unsigned short* __restrict__ h_in,   // bf16 [B*N*H]
    const uint4* __restrict__ kdesc,           // {start, cnt<<20|cm, src0, m0}
    const uint2* __restrict__ erec,
    unsigned short* __restrict__ aggc){        // bf16 [1+nz][128]
  const int orig = blockIdx.x;                 // 8192
  const int x    = orig & 7;                   // XCD (round-robin dispatch)
  const int b    = x >> 1;
  const int lb   = ((x & 1) << 10) + (orig >> 3);   // 0..2047 within batch
  const int key  = (b << 17) + (lb << 6) + (threadIdx.x >> 2);
  const int q    = threadIdx.x & 3;
  uint4 kd = kdesc[key];
  int cnt = (int)(kd.y >> 20);
  if (cnt == 0) return;
  int cm = (int)(kd.y & 0xFFFFFu);
  const unsigned short* hb = h_in + ((size_t)b << 20);

  float fa[32];
  #pragma unroll
  for (int i=0;i<32;++i) fa[i] = 0.f;

#define UNP8(FP, V, M) do { \
  (FP)[0]+=M*bfh((V).x,0); (FP)[1]+=M*bfh((V).x,1); \
  (FP)[2]+=M*bfh((V).y,0); (FP)[3]+=M*bfh((V).y,1); \
  (FP)[4]+=M*bfh((V).z,0); (FP)[5]+=M*bfh((V).z,1); \
  (FP)[6]+=M*bfh((V).w,0); (FP)[7]+=M*bfh((V).w,1); \
} while(0)
#define MAC32(SRC, MB) do { \
  float m_ = __uint_as_float(MB); \
  const uint4* hp_ = (const uint4*)(hb + (((unsigned)(SRC))<<7) + (q<<5)); \
  uint4 v0_ = hp_[0], v1_ = hp_[1], v2_ = hp_[2], v3_ = hp_[3]; \
  UNP8(fa+0,  v0_, m_); UNP8(fa+8,  v1_, m_); \
  UNP8(fa+16, v2_, m_); UNP8(fa+24, v3_, m_); \
} while(0)

  int s = (int)kd.x;
  uint2 rc;
  if (cnt > 1) rc = erec[s+1];
  MAC32(kd.z, kd.w);
  for (int e = 1; e < cnt; ++e) {
    uint2 cur = rc;
    if (e+1 < cnt) rc = erec[s+e+1];
    MAC32(cur.x, cur.y);
  }
#undef MAC32
#undef UNP8

  unsigned short* ap = aggc + ((size_t)cm << 7) + (q<<5);
  #pragma unroll
  for (int c = 0; c < 4; ++c) {
    uint4 pk;
    pk.x = cvtpk(fa[c*8+0], fa[c*8+1]);
    pk.y = cvtpk(fa[c*8+2], fa[c*8+3]);
    pk.z = cvtpk(fa[c*8+4], fa[c*8+5]);
    pk.w = cvtpk(fa[c*8+6], fa[c*8+7]);
    *(uint4*)(ap + c*8) = pk;
  }
}

// ---------------- dense GEMM over compacted A (LDS, 3-deep pipeline) ------
// NOUT=128: MT=128, 1024 threads (16 waves = 4m x 4n, wave 32x32), grid 256.
//   Halves B L2-traffic vs MT=64 and doubles per-iter wall time so the
//   counted-vmcnt lookahead (2 iters) covers L3 latency.
// NOUT=32: MT=64, 512 threads (8 waves = 4m x 2n, wave 16x16), grid 512,
//   fused softmax via padded LDS comb.
// A staged via cmap indirection (empty rows -> zero slot), pre-swizzled
// global source so ds_read_b128 is conflict-free (rule 21 / m97 pattern).

template<int NOUT>
__global__ __launch_bounds__((NOUT==128) ? 1024 : 512, 4) void gemm_k(
    const unsigned short* __restrict__ Agc,    // bf16 [1+nz][128]
    const int* __restrict__ cmap,              // [NKEYS]
    const unsigned short* __restrict__ Wt,     // bf16 [R][NOUT][H]
    const float* __restrict__ mobj,            // [B*N] (NOUT=32)
    unsigned short* __restrict__ h_out,        // bf16 (NOUT=128)
    float* __restrict__ out)                   // fp32 (NOUT=32)
{
  constexpr int MT  = (NOUT==128) ? 128 : 64;
  constexpr int MI  = (NOUT==128) ? 2 : 1;
  constexpr int NIw = (NOUT==128) ? 2 : 1;
  constexpr int NTH = (NOUT==128) ? 1024 : 512;
  __shared__ __align__(16) unsigned short A_s[3][MT*64];    // 48 / 24 KB
  __shared__ __align__(16) unsigned short B_s[3][NOUT*64];  // 48 / 12 KB
  __shared__ int cmap_s[MT*16];                             // 8 / 4 KB
  __shared__ float comb[(NOUT==32) ? 64*33 : 1];            // 8.4 KB (NOUT=32)

  const int tid  = threadIdx.x;
  const int lane = tid & 63;
  const int w    = tid >> 6;
  const int c16  = lane & 15;
  const int g    = lane >> 4;
  const int m0   = blockIdx.x * MT;
  const int mbase = (NOUT==128) ? ((w>>2)<<5) : ((w>>1)<<4);
  const int nbase = (NOUT==128) ? ((w&3)<<5) : ((w&1)<<4);

  // prologue: this tile's cmap entries -> LDS  (MT*16 ints, NTH threads)
  *(int2*)&cmap_s[tid<<1] = *(const int2*)(cmap + m0*16 + (tid<<1));
  __syncthreads();

#define STAGE(KC, BUF) do { \
  const int kc_ = (KC); \
  { /* A: MT*8 16B-units, 1 per thread */ \
    int m_ = tid>>3, u_ = tid&7; \
    int cm_ = cmap_s[(m_<<4) + (kc_>>1)]; \
    glds16((const char*)Agc + ((size_t)cm_<<8) + ((kc_&1)<<7) + ((u_ ^ (m_&7))<<4), \
           &A_s[BUF][tid<<3]); \
  } \
  if constexpr (NOUT==128) { \
    int n_ = tid>>3, u_ = tid&7; \
    glds16((const char*)Wt + ((size_t)((kc_>>1)*128 + n_)<<8) + ((kc_&1)<<7) + ((u_ ^ (n_&7))<<4), \
           &B_s[BUF][tid<<3]); \
  } else { \
    if (w < 4) { \
      int uid_ = (w<<6) + lane; \
      int n_ = uid_>>3, u_ = uid_&7; \
      glds16((const char*)Wt + ((size_t)((kc_>>1)*32 + n_)<<8) + ((kc_&1)<<7) + ((u_ ^ (n_&7))<<4), \
             &B_s[BUF][uid_<<3]); } \
  } \
} while(0)

#define WAIT_MAIN do { \
  if constexpr (NOUT==128) { asm volatile("s_waitcnt vmcnt(4)" ::: "memory"); } \
  else { if (w < 4) asm volatile("s_waitcnt vmcnt(4)" ::: "memory"); \
         else       asm volatile("s_waitcnt vmcnt(2)" ::: "memory"); } \
} while(0)
#define WAIT_T1 do { \
  if constexpr (NOUT==128) { asm volatile("s_waitcnt vmcnt(2)" ::: "memory"); } \
  else { if (w < 4) asm volatile("s_waitcnt vmcnt(2)" ::: "memory"); \
         else       asm volatile("s_waitcnt vmcnt(1)" ::: "memory"); } \
} while(0)

  f32x4 acc[MI][NIw];
  #pragma unroll
  for (int mi=0; mi<MI; ++mi)
    #pragma unroll
    for (int ni=0; ni<NIw; ++ni)
      acc[mi][ni] = f32x4{0.f,0.f,0.f,0.f};

#define COMPUTE(BUF) do { \
  _Pragma("unroll") \
  for (int kk=0; kk<2; ++kk) { \
    short8 af[MI], bfr[NIw]; \
    _Pragma("unroll") \
    for (int mi=0; mi<MI; ++mi) { \
      int m_ = mbase + mi*16 + c16; \
      af[mi] = *(const short8*)((const char*)&A_s[BUF][0] + m_*128 \
               + (((kk<<6) + (g<<4)) ^ ((m_&7)<<4))); } \
    _Pragma("unroll") \
    for (int ni=0; ni<NIw; ++ni) { \
      int n_ = nbase + ni*16 + c16; \
      bfr[ni] = *(const short8*)((const char*)&B_s[BUF][0] + n_*128 \
               + (((kk<<6) + (g<<4)) ^ ((n_&7)<<4))); } \
    _Pragma("unroll") \
    for (int mi=0; mi<MI; ++mi) \
      _Pragma("unroll") \
      for (int ni=0; ni<NIw; ++ni) \
        acc[mi][ni] = __builtin_amdgcn_mfma_f32_16x16x32_bf16(af[mi], bfr[ni], acc[mi][ni], 0,0,0); \
  } \
} while(0)

  STAGE(0, 0);
  STAGE(1, 1);
  for (int kc = 0; kc < 30; ++kc) {
    STAGE(kc+2, (kc+2)%3);
    WAIT_MAIN;
    __builtin_amdgcn_s_barrier();
    COMPUTE(kc%3);
    asm volatile("s_waitcnt lgkmcnt(0)" ::: "memory");
    __builtin_amdgcn_s_barrier();
  }
  // kc = 30
  WAIT_T1;
  __builtin_amdgcn_s_barrier();
  COMPUTE(0);
  asm volatile("s_waitcnt lgkmcnt(0)" ::: "memory");
  __builtin_amdgcn_s_barrier();
  // kc = 31
  asm volatile("s_waitcnt vmcnt(0)" ::: "memory");
  __builtin_amdgcn_s_barrier();
  COMPUTE(1);

  if constexpr (NOUT == 128) {
    #pragma unroll
    for (int mi=0; mi<MI; ++mi)
      #pragma unroll
      for (int ni=0; ni<NIw; ++ni)
        #pragma unroll
        for (int j=0; j<4; ++j) {
          int row = mbase + mi*16 + (g<<2) + j;
          int col = nbase + ni*16 + c16;
          h_out[((size_t)(m0+row)<<7) + col] = f2bf(fmaxf(acc[mi][ni][j], 0.f));
        }
  } else {
    // write acc -> padded comb, then per-row softmax * mask
    #pragma unroll
    for (int j=0; j<4; ++j)
      comb[(mbase + (g<<2) + j)*33 + nbase + c16] = acc[0][0][j];
    __syncthreads();
    if (tid < 64) {
      const int row = tid;
      float v[32];
      #pragma unroll
      for (int c=0; c<32; ++c) v[c] = comb[row*33 + c];
      float mx = v[0];
      #pragma unroll
      for (int c=1; c<32; ++c) mx = fmaxf(mx, v[c]);
      float sm = 0.f;
      #pragma unroll
      for (int c=0; c<32; ++c){ v[c] = __expf(v[c]-mx); sm += v[c]; }
      float sc = mobj[m0+row] / sm;
      float4* op = (float4*)(out + ((size_t)(m0+row)<<5));
      #pragma unroll
      for (int c=0; c<8; ++c)
        op[c] = make_float4(v[4*c]*sc, v[4*c+1]*sc, v[4*c+2]*sc, v[4*c+3]*sc);
    }
  }
#undef STAGE
#undef WAIT_MAIN
#undef WAIT_T1
#undef COMPUTE
}

extern "C" void kernel_launch(void* const* d_in, const int* in_sizes, int n_in,
                              void* d_out, int out_size, void* d_ws, size_t ws_size,
                              hipStream_t stream){
  const int*   cls   = (const int*)  d_in[0];
  // d_in[1] states_objects: unused by reference
  const int*   et    = (const int*)  d_in[2];
  const int*   ec    = (const int*)  d_in[3];
  const float* mobj  = (const float*)d_in[4];
  const float* medge = (const float*)d_in[5];
  const float* emb   = (const float*)d_in[6];
  const float* W1    = (const float*)d_in[7];
  const float* W2    = (const float*)d_in[8];
  const float* W3    = (const float*)d_in[9];
  float* out = (float*)d_out;

  char* ws = (char*)d_ws;
  size_t o = 0;
  auto alloc = [&](size_t bytes)->char*{
    char* p = ws + o;
    o += (bytes + 255) & ~(size_t)255;
    return p;
  };
  unsigned short* hA    = (unsigned short*)alloc((size_t)B_*N_*H_*2);
  unsigned short* hB    = (unsigned short*)alloc((size_t)B_*N_*H_*2);
  unsigned short* W1t   = (unsigned short*)alloc((size_t)R_*H_*H_*2);
  unsigned short* W2t   = (unsigned short*)alloc((size_t)R_*H_*H_*2);
  unsigned short* W3t   = (unsigned short*)alloc((size_t)R_*OUT_*H_*2);
  int*            cnt   = (int*)alloc((size_t)NKEYS*4);
  int*            off   = (int*)alloc((size_t)NKEYS*4);
  int*            offp  = (int*)alloc((size_t)NKEYS*4);
  int*            cidxp = (int*)alloc((size_t)NKEYS*4);
  int*            cmap  = (int*)alloc((size_t)NKEYS*4);
  int*            bsumV = (int*)alloc(512*4);
  int*            bsumF = (int*)alloc(512*4);
  uint4*          kdesc = (uint4*)alloc((size_t)NKEYS*16);
  uint2*          erec  = (uint2*)alloc((size_t)NEDGE*8);
  unsigned short* aggc  = (unsigned short*)alloc(((size_t)NKEYS+1)*H_*2);  // 128 MB
  (void)ws_size; (void)in_sizes; (void)n_in; (void)out_size;

  // CSR build + compaction + keydesc
  hipMemsetAsync(cnt, 0, (size_t)NKEYS*4, stream);
  hipLaunchKernelGGL(hist_k,  dim3(NEDGE/256), dim3(256), 0, stream, et, ec, cnt);
  hipLaunchKernelGGL(scanA_k, dim3(512), dim3(256), 0, stream, cnt, offp, cidxp, bsumV, bsumF);
  hipLaunchKernelGGL(scanB_k, dim3(2),   dim3(256), 0, stream, bsumV, bsumF);
  hipLaunchKernelGGL(scanC_k, dim3(512), dim3(256), 0, stream, offp, cidxp, bsumV, bsumF,
                     cnt, off, cmap, kdesc);
  hipLaunchKernelGGL(fill_k,  dim3(NEDGE/256), dim3(256), 0, stream, et, ec, medge, off, erec, kdesc);

  // h0 = bf16(embed[class]);  W -> bf16 [r][n][k];  zero slot 0 of aggc
  hipLaunchKernelGGL(prep_k, dim3((B_*N_*32 + 2*R_*H_*H_ + R_*OUT_*H_)/256), dim3(256), 0, stream,
                     cls, emb, W1, W2, W3, hA, W1t, W2t, W3t, aggc);

  const int aggGrid = (NKEYS*4)/256;   // 8192
  const int g128    = (B_*N_)/128;     // 256 blocks x 1024 thr
  const int g32     = (B_*N_)/64;      // 512 blocks x 512 thr

  // layer 1
  hipLaunchKernelGGL(agg_k, dim3(aggGrid), dim3(256), 0, stream, hA, kdesc, erec, aggc);
  hipLaunchKernelGGL((gemm_k<128>), dim3(g128), dim3(1024), 0, stream,
                     aggc, cmap, W1t, (const float*)nullptr, hB, (float*)nullptr);
  // layer 2
  hipLaunchKernelGGL(agg_k, dim3(aggGrid), dim3(256), 0, stream, hB, kdesc, erec, aggc);
  hipLaunchKernelGGL((gemm_k<128>), dim3(g128), dim3(1024), 0, stream,
                     aggc, cmap, W2t, (const float*)nullptr, hA, (float*)nullptr);
  // layer 3 (+ fused softmax * mask)
  hipLaunchKernelGGL(agg_k, dim3(aggGrid), dim3(256), 0, stream, hA, kdesc, erec, aggc);
  hipLaunchKernelGGL((gemm_k<32>), dim3(g32), dim3(512), 0, stream,
                     aggc, cmap, W3t, mobj, (unsigned short*)nullptr, out);
}

// Round 12
// 237.808 us; speedup vs baseline: 1.8984x; 1.1199x over previous
//
#include <hip/hip_runtime.h>

typedef __attribute__((ext_vector_type(4))) float f32x4;
typedef __attribute__((ext_vector_type(8))) short short8;

#define B_ 4
#define N_ 8192
#define E_ 131072
#define R_ 16
#define H_ 128
#define OUT_ 32
#define NKEYS (B_*N_*R_)   /* 524288 */
#define NEDGE (B_*E_)      /* 524288 */

__device__ __forceinline__ unsigned short f2bf(float f){
  unsigned int u = __float_as_uint(f);
  u = (u + 0x7fffu + ((u>>16)&1u)) >> 16;
  return (unsigned short)u;
}
__device__ __forceinline__ float bfh(unsigned u, int hi){
  return __uint_as_float(hi ? (u & 0xffff0000u) : (u << 16));
}
__device__ __forceinline__ unsigned cvtpk(float lo, float hi){
  unsigned r;
  asm("v_cvt_pk_bf16_f32 %0, %1, %2" : "=v"(r) : "v"(lo), "v"(hi));
  return r;
}
__device__ __forceinline__ void glds16(const void* g, void* l){
  __builtin_amdgcn_global_load_lds((const __attribute__((address_space(1))) unsigned int*)g,
                                   (__attribute__((address_space(3))) unsigned int*)l,
                                   16, 0, 0);
}

// ---------------- CSR build: key = node*16 + rel, node = b*8192+dst -------

__global__ void hist_k(const int* __restrict__ et, const int* __restrict__ ec,
                       int* __restrict__ cnt){
  int e = blockIdx.x*256 + threadIdx.x;
  int b = e >> 17;                  // E = 2^17
  int dst = et[2*e+1];
  int r  = ec[e];
  atomicAdd(&cnt[(((b<<13)+dst)<<4) + r], 1);
}

// pass A: per-block exclusive scans of cnt values AND of (cnt!=0) flags
__global__ void scanA_k(const int* __restrict__ cnt,
                        int* __restrict__ offp, int* __restrict__ cidxp,
                        int* __restrict__ bsumV, int* __restrict__ bsumF){
  __shared__ int ldsV[256], ldsF[256];
  int t = threadIdx.x;
  int base = blockIdx.x*1024 + t*4;
  int4 v = *(const int4*)(cnt + base);
  int4 f; f.x = v.x!=0; f.y = v.y!=0; f.z = v.z!=0; f.w = v.w!=0;
  ldsV[t] = v.x+v.y+v.z+v.w;
  ldsF[t] = f.x+f.y+f.z+f.w;
  __syncthreads();
  for (int off=1; off<256; off<<=1){
    int xv = (t>=off) ? ldsV[t-off] : 0;
    int xf = (t>=off) ? ldsF[t-off] : 0;
    __syncthreads();
    ldsV[t] += xv; ldsF[t] += xf;
    __syncthreads();
  }
  if (t==255){ bsumV[blockIdx.x] = ldsV[255]; bsumF[blockIdx.x] = ldsF[255]; }
  int pv = (t==0) ? 0 : ldsV[t-1];
  int pf = (t==0) ? 0 : ldsF[t-1];
  int4 ov; ov.x = pv; ov.y = ov.x+v.x; ov.z = ov.y+v.y; ov.w = ov.z+v.z;
  int4 of; of.x = pf; of.y = of.x+f.x; of.z = of.y+f.y; of.w = of.z+f.z;
  *(int4*)(offp  + base) = ov;
  *(int4*)(cidxp + base) = of;
}

// pass B: single-block scan of one 512-entry bsum array (grid=2: V then F)
__global__ void scanB_k(int* __restrict__ bsumV, int* __restrict__ bsumF){
  int* bs = blockIdx.x ? bsumF : bsumV;
  __shared__ int lds[256];
  int t = threadIdx.x;
  int2 v = *(const int2*)(bs + t*2);
  lds[t] = v.x+v.y;
  __syncthreads();
  for (int off=1; off<256; off<<=1){
    int x = (t>=off) ? lds[t-off] : 0;
    __syncthreads();
    lds[t] += x;
    __syncthreads();
  }
  int pre = (t==0) ? 0 : lds[t-1];
  int2 o; o.x = pre; o.y = pre + v.x;
  *(int2*)(bs + t*2) = o;
}

// pass C: finalize off (starts), kdesc.xy = {start, cnt<<20|cm}, and the
// per-layer virtual-row maps (default: aggc row = aggcRow + cm).
__global__ void scanC_k(const int* __restrict__ offp, const int* __restrict__ cidxp,
                        const int* __restrict__ bsumV, const int* __restrict__ bsumF,
                        const int* __restrict__ cnt,
                        int* __restrict__ off,
                        int* __restrict__ cmapA, int* __restrict__ cmapB,
                        uint4* __restrict__ kdesc, int aggcRow){
  int t = threadIdx.x;
  int base = blockIdx.x*1024 + t*4;
  int addV = bsumV[blockIdx.x];
  int addF = bsumF[blockIdx.x] + 1;      // +1: slot 0 is the zero block
  int4 o  = *(const int4*)(offp + base);
  o.x+=addV; o.y+=addV; o.z+=addV; o.w+=addV;
  *(int4*)(off + base) = o;
  int4 cx = *(const int4*)(cidxp + base);
  int4 cv = *(const int4*)(cnt + base);
  int4 cm;
  cm.x = cv.x ? cx.x+addF : 0;
  cm.y = cv.y ? cx.y+addF : 0;
  cm.z = cv.z ? cx.z+addF : 0;
  cm.w = cv.w ? cx.w+addF : 0;
  int4 vr;
  vr.x = aggcRow + cm.x; vr.y = aggcRow + cm.y;
  vr.z = aggcRow + cm.z; vr.w = aggcRow + cm.w;
  *(int4*)(cmapA + base) = vr;
  *(int4*)(cmapB + base) = vr;
  *(int2*)&kdesc[base+0].x = make_int2(o.x, (cv.x<<20)|cm.x);
  *(int2*)&kdesc[base+1].x = make_int2(o.y, (cv.y<<20)|cm.y);
  *(int2*)&kdesc[base+2].x = make_int2(o.z, (cv.z<<20)|cm.z);
  *(int2*)&kdesc[base+3].x = make_int2(o.w, (cv.w<<20)|cm.w);
}

// fill consumes off (start -> end) via atomicAdd; first edge lands in
// keydesc.zw; single-edge unit-mask keys get cmap pointed at the h row.
__global__ void fill_k(const int* __restrict__ et, const int* __restrict__ ec,
                       const float* __restrict__ me, int* __restrict__ off,
                       uint2* __restrict__ erec, uint4* __restrict__ kdesc,
                       int* __restrict__ cmapA, int* __restrict__ cmapB,
                       int hARow, int hBRow){
  int e = blockIdx.x*256 + threadIdx.x;
  int b = e >> 17;
  int src = et[2*e];
  int dst = et[2*e+1];
  int r  = ec[e];
  int key = (((b<<13)+dst)<<4) + r;
  unsigned mbits = __float_as_uint(me[e]);
  int pos = atomicAdd(&off[key], 1);
  erec[pos] = make_uint2((unsigned)src, mbits);
  uint2 kxy = *(const uint2*)&kdesc[key].x;
  if (pos == (int)kxy.x) {
    *(uint2*)&kdesc[key].z = make_uint2((unsigned)src, mbits);
    if ((kxy.y >> 20) == 1u && mbits == 0x3f800000u) {
      int noderow = (b<<13) + src;
      cmapA[key] = hARow + noderow;      // A-row IS the h row: zero-copy
      cmapB[key] = hBRow + noderow;
    }
  }
}

// ---------------- feature prep (embed + 3x W-transpose + zero slot) -------

__global__ void prep_k(const int* __restrict__ cls, const float* __restrict__ emb,
                       const float* __restrict__ W1, const float* __restrict__ W2,
                       const float* __restrict__ W3,
                       unsigned short* __restrict__ h,
                       unsigned short* __restrict__ W1t,
                       unsigned short* __restrict__ W2t,
                       unsigned short* __restrict__ W3t,
                       unsigned short* __restrict__ aggc){
  int t = blockIdx.x*256 + threadIdx.x;
  if (blockIdx.x == 0 && threadIdx.x < 16) {
    *(uint4*)((char*)aggc + threadIdx.x*16) = make_uint4(0,0,0,0);  // zero slot
  }
  if (t < B_*N_*32) {
    int node = t>>5, c = t&31;
    int cl = cls[node];
    float4 v = *(const float4*)(emb + cl*H_ + c*4);
    uint2 o;
    o.x = f2bf(v.x) | ((unsigned int)f2bf(v.y)<<16);
    o.y = f2bf(v.z) | ((unsigned int)f2bf(v.w)<<16);
    *(uint2*)(h + node*H_ + c*4) = o;
  } else {
    int u = t - B_*N_*32;
    if (u < R_*H_*H_) {
      int k = u & 127, n = (u>>7) & 127, r = u >> 14;
      W1t[u] = f2bf(W1[(r*H_ + k)*H_ + n]);
    } else if (u < 2*R_*H_*H_) {
      int u2 = u - R_*H_*H_;
      int k = u2 & 127, n = (u2>>7) & 127, r = u2 >> 14;
      W2t[u2] = f2bf(W2[(r*H_ + k)*H_ + n]);
    } else {
      int u2 = u - 2*R_*H_*H_;
      if (u2 < R_*OUT_*H_) {
        int k = u2 & 127, n = (u2>>7) & 31, r = u2 >> 12;
        W3t[u2] = f2bf(W3[(r*H_ + k)*OUT_ + n]);
      }
    }
  }
}

// ---------------- aggregation (skips single-edge unit-mask keys) ----------
// XCD x = blk&7 serves batch x>>1 only -> per-XCD h slice = 2MB < 4MB L2.

__global__ __launch_bounds__(256) void agg_k(
    const unsigned short* __restrict__ h_in,   // bf16 [B*N*H]
    const uint4* __restrict__ kdesc,           // {start, cnt<<20|cm, src0, m0}
    const uint2* __restrict__ erec,
    unsigned short* __restrict__ aggc){        // bf16 [1+nz][128]
  const int orig = blockIdx.x;                 // 8192
  const int x    = orig & 7;                   // XCD (round-robin dispatch)
  const int b    = x >> 1;
  const int lb   = ((x & 1) << 10) + (orig >> 3);   // 0..2047 within batch
  const int key  = (b << 17) + (lb << 6) + (threadIdx.x >> 2);
  const int q    = threadIdx.x & 3;
  uint4 kd = kdesc[key];
  int cnt = (int)(kd.y >> 20);
  if (cnt == 0) return;
  if (cnt == 1 && kd.w == 0x3f800000u) return;   // zero-copy key: gemm reads h
  int cm = (int)(kd.y & 0xFFFFFu);
  const unsigned short* hb = h_in + ((size_t)b << 20);

  float fa[32];
  #pragma unroll
  for (int i=0;i<32;++i) fa[i] = 0.f;

#define UNP8(FP, V, M) do { \
  (FP)[0]+=M*bfh((V).x,0); (FP)[1]+=M*bfh((V).x,1); \
  (FP)[2]+=M*bfh((V).y,0); (FP)[3]+=M*bfh((V).y,1); \
  (FP)[4]+=M*bfh((V).z,0); (FP)[5]+=M*bfh((V).z,1); \
  (FP)[6]+=M*bfh((V).w,0); (FP)[7]+=M*bfh((V).w,1); \
} while(0)
#define MAC32(SRC, MB) do { \
  float m_ = __uint_as_float(MB); \
  const uint4* hp_ = (const uint4*)(hb + (((unsigned)(SRC))<<7) + (q<<5)); \
  uint4 v0_ = hp_[0], v1_ = hp_[1], v2_ = hp_[2], v3_ = hp_[3]; \
  UNP8(fa+0,  v0_, m_); UNP8(fa+8,  v1_, m_); \
  UNP8(fa+16, v2_, m_); UNP8(fa+24, v3_, m_); \
} while(0)

  int s = (int)kd.x;
  uint2 rc;
  if (cnt > 1) rc = erec[s+1];
  MAC32(kd.z, kd.w);
  for (int e = 1; e < cnt; ++e) {
    uint2 cur = rc;
    if (e+1 < cnt) rc = erec[s+e+1];
    MAC32(cur.x, cur.y);
  }
#undef MAC32
#undef UNP8

  unsigned short* ap = aggc + ((size_t)cm << 7) + (q<<5);
  #pragma unroll
  for (int c = 0; c < 4; ++c) {
    uint4 pk;
    pk.x = cvtpk(fa[c*8+0], fa[c*8+1]);
    pk.y = cvtpk(fa[c*8+2], fa[c*8+3]);
    pk.z = cvtpk(fa[c*8+4], fa[c*8+5]);
    pk.w = cvtpk(fa[c*8+6], fa[c*8+7]);
    *(uint4*)(ap + c*8) = pk;
  }
}

// ---------------- dense GEMM over virtual-row A (LDS, 3-deep pipeline) ----
// A rows live anywhere in ws (aggc slots OR h rows, all 256B-aligned):
// cmap[key] is the virtual row index from ws base. NOUT=128: MT=128, 1024
// thr, grid 256. NOUT=32: MT=64, 512 thr, grid 512, fused softmax.
// Counted vmcnt (never 0 in main loop); pre-swizzled glds source (rule 21).

template<int NOUT>
__global__ __launch_bounds__((NOUT==128) ? 1024 : 512, 4) void gemm_k(
    const unsigned short* __restrict__ base,   // ws base (row 0)
    const int* __restrict__ cmap,              // [NKEYS] virtual rows
    const unsigned short* __restrict__ Wt,     // bf16 [R][NOUT][H]
    const float* __restrict__ mobj,            // [B*N] (NOUT=32)
    unsigned short* __restrict__ h_out,        // bf16 (NOUT=128)
    float* __restrict__ out)                   // fp32 (NOUT=32)
{
  constexpr int MT  = (NOUT==128) ? 128 : 64;
  constexpr int MI  = (NOUT==128) ? 2 : 1;
  constexpr int NIw = (NOUT==128) ? 2 : 1;
  __shared__ __align__(16) unsigned short A_s[3][MT*64];    // 48 / 24 KB
  __shared__ __align__(16) unsigned short B_s[3][NOUT*64];  // 48 / 12 KB
  __shared__ int cmap_s[MT*16];                             // 8 / 4 KB
  __shared__ float comb[(NOUT==32) ? 64*33 : 1];            // 8.4 KB (NOUT=32)

  const int tid  = threadIdx.x;
  const int lane = tid & 63;
  const int w    = tid >> 6;
  const int c16  = lane & 15;
  const int g    = lane >> 4;
  const int m0   = blockIdx.x * MT;
  const int mbase = (NOUT==128) ? ((w>>2)<<5) : ((w>>1)<<4);
  const int nbase = (NOUT==128) ? ((w&3)<<5) : ((w&1)<<4);

  *(int2*)&cmap_s[tid<<1] = *(const int2*)(cmap + m0*16 + (tid<<1));
  __syncthreads();

#define STAGE(KC, BUF) do { \
  const int kc_ = (KC); \
  { \
    int m_ = tid>>3, u_ = tid&7; \
    int cm_ = cmap_s[(m_<<4) + (kc_>>1)]; \
    glds16((const char*)base + ((size_t)cm_<<8) + ((kc_&1)<<7) + ((u_ ^ (m_&7))<<4), \
           &A_s[BUF][tid<<3]); \
  } \
  if constexpr (NOUT==128) { \
    int n_ = tid>>3, u_ = tid&7; \
    glds16((const char*)Wt + ((size_t)((kc_>>1)*128 + n_)<<8) + ((kc_&1)<<7) + ((u_ ^ (n_&7))<<4), \
           &B_s[BUF][tid<<3]); \
  } else { \
    if (w < 4) { \
      int uid_ = (w<<6) + lane; \
      int n_ = uid_>>3, u_ = uid_&7; \
      glds16((const char*)Wt + ((size_t)((kc_>>1)*32 + n_)<<8) + ((kc_&1)<<7) + ((u_ ^ (n_&7))<<4), \
             &B_s[BUF][uid_<<3]); } \
  } \
} while(0)

#define WAIT_MAIN do { \
  if constexpr (NOUT==128) { asm volatile("s_waitcnt vmcnt(4)" ::: "memory"); } \
  else { if (w < 4) asm volatile("s_waitcnt vmcnt(4)" ::: "memory"); \
         else       asm volatile("s_waitcnt vmcnt(2)" ::: "memory"); } \
} while(0)
#define WAIT_T1 do { \
  if constexpr (NOUT==128) { asm volatile("s_waitcnt vmcnt(2)" ::: "memory"); } \
  else { if (w < 4) asm volatile("s_waitcnt vmcnt(2)" ::: "memory"); \
         else       asm volatile("s_waitcnt vmcnt(1)" ::: "memory"); } \
} while(0)

  f32x4 acc[MI][NIw];
  #pragma unroll
  for (int mi=0; mi<MI; ++mi)
    #pragma unroll
    for (int ni=0; ni<NIw; ++ni)
      acc[mi][ni] = f32x4{0.f,0.f,0.f,0.f};

#define COMPUTE(BUF) do { \
  _Pragma("unroll") \
  for (int kk=0; kk<2; ++kk) { \
    short8 af[MI], bfr[NIw]; \
    _Pragma("unroll") \
    for (int mi=0; mi<MI; ++mi) { \
      int m_ = mbase + mi*16 + c16; \
      af[mi] = *(const short8*)((const char*)&A_s[BUF][0] + m_*128 \
               + (((kk<<6) + (g<<4)) ^ ((m_&7)<<4))); } \
    _Pragma("unroll") \
    for (int ni=0; ni<NIw; ++ni) { \
      int n_ = nbase + ni*16 + c16; \
      bfr[ni] = *(const short8*)((const char*)&B_s[BUF][0] + n_*128 \
               + (((kk<<6) + (g<<4)) ^ ((n_&7)<<4))); } \
    _Pragma("unroll") \
    for (int mi=0; mi<MI; ++mi) \
      _Pragma("unroll") \
      for (int ni=0; ni<NIw; ++ni) \
        acc[mi][ni] = __builtin_amdgcn_mfma_f32_16x16x32_bf16(af[mi], bfr[ni], acc[mi][ni], 0,0,0); \
  } \
} while(0)

  STAGE(0, 0);
  STAGE(1, 1);
  for (int kc = 0; kc < 30; ++kc) {
    STAGE(kc+2, (kc+2)%3);
    WAIT_MAIN;
    __builtin_amdgcn_s_barrier();
    COMPUTE(kc%3);
    asm volatile("s_waitcnt lgkmcnt(0)" ::: "memory");
    __builtin_amdgcn_s_barrier();
  }
  // kc = 30
  WAIT_T1;
  __builtin_amdgcn_s_barrier();
  COMPUTE(0);
  asm volatile("s_waitcnt lgkmcnt(0)" ::: "memory");
  __builtin_amdgcn_s_barrier();
  // kc = 31
  asm volatile("s_waitcnt vmcnt(0)" ::: "memory");
  __builtin_amdgcn_s_barrier();
  COMPUTE(1);

  if constexpr (NOUT == 128) {
    #pragma unroll
    for (int mi=0; mi<MI; ++mi)
      #pragma unroll
      for (int ni=0; ni<NIw; ++ni)
        #pragma unroll
        for (int j=0; j<4; ++j) {
          int row = mbase + mi*16 + (g<<2) + j;
          int col = nbase + ni*16 + c16;
          h_out[((size_t)(m0+row)<<7) + col] = f2bf(fmaxf(acc[mi][ni][j], 0.f));
        }
  } else {
    #pragma unroll
    for (int j=0; j<4; ++j)
      comb[(mbase + (g<<2) + j)*33 + nbase + c16] = acc[0][0][j];
    __syncthreads();
    if (tid < 64) {
      const int row = tid;
      float v[32];
      #pragma unroll
      for (int c=0; c<32; ++c) v[c] = comb[row*33 + c];
      float mx = v[0];
      #pragma unroll
      for (int c=1; c<32; ++c) mx = fmaxf(mx, v[c]);
      float sm = 0.f;
      #pragma unroll
      for (int c=0; c<32; ++c){ v[c] = __expf(v[c]-mx); sm += v[c]; }
      float sc = mobj[m0+row] / sm;
      float4* op = (float4*)(out + ((size_t)(m0+row)<<5));
      #pragma unroll
      for (int c=0; c<8; ++c)
        op[c] = make_float4(v[4*c]*sc, v[4*c+1]*sc, v[4*c+2]*sc, v[4*c+3]*sc);
    }
  }
#undef STAGE
#undef WAIT_MAIN
#undef WAIT_T1
#undef COMPUTE
}

extern "C" void kernel_launch(void* const* d_in, const int* in_sizes, int n_in,
                              void* d_out, int out_size, void* d_ws, size_t ws_size,
                              hipStream_t stream){
  const int*   cls   = (const int*)  d_in[0];
  // d_in[1] states_objects: unused by reference
  const int*   et    = (const int*)  d_in[2];
  const int*   ec    = (const int*)  d_in[3];
  const float* mobj  = (const float*)d_in[4];
  const float* medge = (const float*)d_in[5];
  const float* emb   = (const float*)d_in[6];
  const float* W1    = (const float*)d_in[7];
  const float* W2    = (const float*)d_in[8];
  const float* W3    = (const float*)d_in[9];
  float* out = (float*)d_out;

  char* ws = (char*)d_ws;
  size_t o = 0;
  auto alloc = [&](size_t bytes)->char*{
    char* p = ws + o;
    o += (bytes + 255) & ~(size_t)255;
    return p;
  };
  unsigned short* hA    = (unsigned short*)alloc((size_t)B_*N_*H_*2);
  unsigned short* hB    = (unsigned short*)alloc((size_t)B_*N_*H_*2);
  unsigned short* W1t   = (unsigned short*)alloc((size_t)R_*H_*H_*2);
  unsigned short* W2t   = (unsigned short*)alloc((size_t)R_*H_*H_*2);
  unsigned short* W3t   = (unsigned short*)alloc((size_t)R_*OUT_*H_*2);
  int*            cnt   = (int*)alloc((size_t)NKEYS*4);
  int*            off   = (int*)alloc((size_t)NKEYS*4);
  int*            offp  = (int*)alloc((size_t)NKEYS*4);
  int*            cidxp = (int*)alloc((size_t)NKEYS*4);
  int*            cmapA = (int*)alloc((size_t)NKEYS*4);
  int*            cmapB = (int*)alloc((size_t)NKEYS*4);
  int*            bsumV = (int*)alloc(512*4);
  int*            bsumF = (int*)alloc(512*4);
  uint4*          kdesc = (uint4*)alloc((size_t)NKEYS*16);
  uint2*          erec  = (uint2*)alloc((size_t)NEDGE*8);
  unsigned short* aggc  = (unsigned short*)alloc(((size_t)NKEYS+1)*H_*2);  // 128 MB
  (void)ws_size; (void)in_sizes; (void)n_in; (void)out_size;

  const int hARow   = (int)(((char*)hA   - ws) >> 8);   // 0
  const int hBRow   = (int)(((char*)hB   - ws) >> 8);
  const int aggcRow = (int)(((char*)aggc - ws) >> 8);
  const unsigned short* vbase = (const unsigned short*)ws;

  // CSR build + compaction + keydesc + virtual-row maps
  hipMemsetAsync(cnt, 0, (size_t)NKEYS*4, stream);
  hipLaunchKernelGGL(hist_k,  dim3(NEDGE/256), dim3(256), 0, stream, et, ec, cnt);
  hipLaunchKernelGGL(scanA_k, dim3(512), dim3(256), 0, stream, cnt, offp, cidxp, bsumV, bsumF);
  hipLaunchKernelGGL(scanB_k, dim3(2),   dim3(256), 0, stream, bsumV, bsumF);
  hipLaunchKernelGGL(scanC_k, dim3(512), dim3(256), 0, stream, offp, cidxp, bsumV, bsumF,
                     cnt, off, cmapA, cmapB, kdesc, aggcRow);
  hipLaunchKernelGGL(fill_k,  dim3(NEDGE/256), dim3(256), 0, stream, et, ec, medge, off,
                     erec, kdesc, cmapA, cmapB, hARow, hBRow);

  // h0 = bf16(embed[class]);  W -> bf16 [r][n][k];  zero slot 0 of aggc
  hipLaunchKernelGGL(prep_k, dim3((B_*N_*32 + 2*R_*H_*H_ + R_*OUT_*H_)/256), dim3(256), 0, stream,
                     cls, emb, W1, W2, W3, hA, W1t, W2t, W3t, aggc);

  const int aggGrid = (NKEYS*4)/256;   // 8192
  const int g128    = (B_*N_)/128;     // 256 blocks x 1024 thr
  const int g32     = (B_*N_)/64;      // 512 blocks x 512 thr

  // layer 1 (h = hA, zero-copy rows via cmapA)
  hipLaunchKernelGGL(agg_k, dim3(aggGrid), dim3(256), 0, stream, hA, kdesc, erec, aggc);
  hipLaunchKernelGGL((gemm_k<128>), dim3(g128), dim3(1024), 0, stream,
                     vbase, cmapA, W1t, (const float*)nullptr, hB, (float*)nullptr);
  // layer 2 (h = hB)
  hipLaunchKernelGGL(agg_k, dim3(aggGrid), dim3(256), 0, stream, hB, kdesc, erec, aggc);
  hipLaunchKernelGGL((gemm_k<128>), dim3(g128), dim3(1024), 0, stream,
                     vbase, cmapB, W2t, (const float*)nullptr, hA, (float*)nullptr);
  // layer 3 (h = hA, + fused softmax * mask)
  hipLaunchKernelGGL(agg_k, dim3(aggGrid), dim3(256), 0, stream, hA, kdesc, erec, aggc);
  hipLaunchKernelGGL((gemm_k<32>), dim3(g32), dim3(512), 0, stream,
                     vbase, cmapA, W3t, mobj, (unsigned short*)nullptr, out);
}

// Round 15
// 207.193 us; speedup vs baseline: 2.1790x; 1.1478x over previous
//
#include <hip/hip_runtime.h>

typedef __attribute__((ext_vector_type(4))) float f32x4;
typedef __attribute__((ext_vector_type(8))) short short8;

#define B_ 4
#define N_ 8192
#define E_ 131072
#define R_ 16
#define H_ 128
#define OUT_ 32
#define NKEYS (B_*N_*R_)   /* 524288 */
#define NEDGE (B_*E_)      /* 524288 */
#define NEXT_MASK 0x7FFFFu /* 19 bits: edge index 0..524287 */

__device__ __forceinline__ unsigned short f2bf(float f){
  unsigned int u = __float_as_uint(f);
  u = (u + 0x7fffu + ((u>>16)&1u)) >> 16;
  return (unsigned short)u;
}
__device__ __forceinline__ float bfh(unsigned u, int hi){
  return __uint_as_float(hi ? (u & 0xffff0000u) : (u << 16));
}
__device__ __forceinline__ unsigned cvtpk(float lo, float hi){
  unsigned r;
  asm("v_cvt_pk_bf16_f32 %0, %1, %2" : "=v"(r) : "v"(lo), "v"(hi));
  return r;
}
__device__ __forceinline__ void glds16(const void* g, void* l){
  __builtin_amdgcn_global_load_lds((const __attribute__((address_space(1))) unsigned int*)g,
                                   (__attribute__((address_space(3))) unsigned int*)l,
                                   16, 0, 0);
}

// ---------------- edge chains: head[key] -> linked list over edges --------
// key = (((b<<13)+dst)<<4) + rel.  link[e] = (src<<19) | next_edge;
// next == self  means end-of-chain.

__global__ void link_k(const int* __restrict__ et, const int* __restrict__ ec,
                       int* __restrict__ head, unsigned* __restrict__ link){
  int e = blockIdx.x*256 + threadIdx.x;
  int b = e >> 17;                  // E = 2^17
  int2 sd = *(const int2*)(et + 2*e);
  int r  = ec[e];
  int key = (((b<<13)+sd.y)<<4) + r;
  int old = atomicExch(&head[key], e);
  unsigned nxt = (old < 0) ? (unsigned)e : (unsigned)old;
  link[e] = (((unsigned)sd.x) << 19) | nxt;
}

// ---------------- cmap: virtual A-row per (key, layer-input) --------------
// empty -> aggc slot 0 (the ZERO BLOCK; row index aggcRow — BUGFIX r15:
// rounds 13/14 used 0, which is hA node 0's row, injecting garbage for the
// 37% empty keys; identical absmax across both rounds fingered this);
// single edge with mask==1 -> the h row itself (zero-copy); otherwise
// direct-mapped aggc slot 1+key.

__global__ void cmap_k(const int* __restrict__ head, const unsigned* __restrict__ link,
                       const float* __restrict__ me,
                       int* __restrict__ cmapA, int* __restrict__ cmapB,
                       int hARow, int hBRow, int aggcRow){
  int key = blockIdx.x*256 + threadIdx.x;
  int hd = head[key];
  int vA = aggcRow, vB = aggcRow;          // zero slot
  if (hd >= 0) {
    unsigned lk = link[hd];
    int nxt = (int)(lk & NEXT_MASK);
    if (nxt == hd && me[hd] == 1.0f) {
      int noderow = ((key >> 17) << 13) + (int)(lk >> 19);
      vA = hARow + noderow;
      vB = hBRow + noderow;
    } else {
      vA = aggcRow + 1 + key;
      vB = vA;
    }
  }
  cmapA[key] = vA;
  cmapB[key] = vB;
}

// ---------------- feature prep (embed + 3x W-transpose + zero slot) -------

__global__ void prep_k(const int* __restrict__ cls, const float* __restrict__ emb,
                       const float* __restrict__ W1, const float* __restrict__ W2,
                       const float* __restrict__ W3,
                       unsigned short* __restrict__ h,
                       unsigned short* __restrict__ W1t,
                       unsigned short* __restrict__ W2t,
                       unsigned short* __restrict__ W3t,
                       unsigned short* __restrict__ aggc){
  int t = blockIdx.x*256 + threadIdx.x;
  if (blockIdx.x == 0 && threadIdx.x < 16) {
    *(uint4*)((char*)aggc + threadIdx.x*16) = make_uint4(0,0,0,0);  // zero slot
  }
  if (t < B_*N_*32) {
    int node = t>>5, c = t&31;
    int cl = cls[node];
    float4 v = *(const float4*)(emb + cl*H_ + c*4);
    uint2 o;
    o.x = f2bf(v.x) | ((unsigned int)f2bf(v.y)<<16);
    o.y = f2bf(v.z) | ((unsigned int)f2bf(v.w)<<16);
    *(uint2*)(h + node*H_ + c*4) = o;
  } else {
    int u = t - B_*N_*32;
    if (u < R_*H_*H_) {
      int k = u & 127, n = (u>>7) & 127, r = u >> 14;
      W1t[u] = f2bf(W1[(r*H_ + k)*H_ + n]);
    } else if (u < 2*R_*H_*H_) {
      int u2 = u - R_*H_*H_;
      int k = u2 & 127, n = (u2>>7) & 127, r = u2 >> 14;
      W2t[u2] = f2bf(W2[(r*H_ + k)*H_ + n]);
    } else {
      int u2 = u - 2*R_*H_*H_;
      if (u2 < R_*OUT_*H_) {
        int k = u2 & 127, n = (u2>>7) & 31, r = u2 >> 12;
        W3t[u2] = f2bf(W3[(r*H_ + k)*OUT_ + n]);
      }
    }
  }
}

// ---------------- aggregation (chain walk; skips zero-copy keys) ----------
// XCD x = blk&7 serves batch x>>1 only -> per-XCD h slice = 2MB < 4MB L2.

__global__ __launch_bounds__(256) void agg_k(
    const unsigned short* __restrict__ h_in,   // bf16 [B*N*H]
    const int* __restrict__ head,
    const unsigned* __restrict__ link,
    const float* __restrict__ me,
    unsigned short* __restrict__ aggc){        // bf16 [1+NKEYS][128]
  const int orig = blockIdx.x;                 // 8192
  const int x    = orig & 7;                   // XCD (round-robin dispatch)
  const int b    = x >> 1;
  const int lb   = ((x & 1) << 10) + (orig >> 3);   // 0..2047 within batch
  const int key  = (b << 17) + (lb << 6) + (threadIdx.x >> 2);
  const int q    = threadIdx.x & 3;
  int hd = head[key];
  if (hd < 0) return;
  unsigned lk = link[hd];
  int nxt = (int)(lk & NEXT_MASK);
  float m0 = me[hd];
  if (nxt == hd && m0 == 1.0f) return;         // zero-copy key: gemm reads h
  const unsigned short* hb = h_in + ((size_t)b << 20);

  float fa[32];
  #pragma unroll
  for (int i=0;i<32;++i) fa[i] = 0.f;

#define UNP8(FP, V, M) do { \
  (FP)[0]+=M*bfh((V).x,0); (FP)[1]+=M*bfh((V).x,1); \
  (FP)[2]+=M*bfh((V).y,0); (FP)[3]+=M*bfh((V).y,1); \
  (FP)[4]+=M*bfh((V).z,0); (FP)[5]+=M*bfh((V).z,1); \
  (FP)[6]+=M*bfh((V).w,0); (FP)[7]+=M*bfh((V).w,1); \
} while(0)
#define MAC32(SRC, M) do { \
  const uint4* hp_ = (const uint4*)(hb + (((unsigned)(SRC))<<7) + (q<<5)); \
  uint4 v0_ = hp_[0], v1_ = hp_[1], v2_ = hp_[2], v3_ = hp_[3]; \
  UNP8(fa+0,  v0_, M); UNP8(fa+8,  v1_, M); \
  UNP8(fa+16, v2_, M); UNP8(fa+24, v3_, M); \
} while(0)

  int cur = hd;
  unsigned clk = lk;
  float cm = m0;
  for (;;) {
    int src = (int)(clk >> 19);
    MAC32(src, cm);
    int nx = (int)(clk & NEXT_MASK);
    if (nx == cur) break;
    cur = nx;
    clk = link[cur];
    cm  = me[cur];
  }
#undef MAC32
#undef UNP8

  unsigned short* ap = aggc + (((size_t)(1 + key)) << 7) + (q<<5);
  #pragma unroll
  for (int c = 0; c < 4; ++c) {
    uint4 pk;
    pk.x = cvtpk(fa[c*8+0], fa[c*8+1]);
    pk.y = cvtpk(fa[c*8+2], fa[c*8+3]);
    pk.z = cvtpk(fa[c*8+4], fa[c*8+5]);
    pk.w = cvtpk(fa[c*8+6], fa[c*8+7]);
    *(uint4*)(ap + c*8) = pk;
  }
}

// ---------------- dense GEMM over virtual-row A (LDS, 3-deep pipeline) ----
// A rows live anywhere in ws (aggc slots OR h rows, all 256B-aligned):
// cmap[key] is the virtual row index from ws base. NOUT=128: MT=128, 1024
// thr, grid 256. NOUT=32: MT=64, 512 thr, grid 512, fused softmax;
// A-staging is ONE 16B unit per thread (r14 fix, kept).
// Counted vmcnt (never 0 in main loop); pre-swizzled glds source (rule 21).

template<int NOUT>
__global__ __launch_bounds__((NOUT==128) ? 1024 : 512, 4) void gemm_k(
    const unsigned short* __restrict__ base,   // ws base (row 0)
    const int* __restrict__ cmap,              // [NKEYS] virtual rows
    const unsigned short* __restrict__ Wt,     // bf16 [R][NOUT][H]
    const float* __restrict__ mobj,            // [B*N] (NOUT=32)
    unsigned short* __restrict__ h_out,        // bf16 (NOUT=128)
    float* __restrict__ out)                   // fp32 (NOUT=32)
{
  constexpr int MT  = (NOUT==128) ? 128 : 64;
  constexpr int MI  = (NOUT==128) ? 2 : 1;
  constexpr int NIw = (NOUT==128) ? 2 : 1;
  __shared__ __align__(16) unsigned short A_s[3][MT*64];    // 48 / 24 KB
  __shared__ __align__(16) unsigned short B_s[3][NOUT*64];  // 48 / 12 KB
  __shared__ int cmap_s[MT*16];                             // 8 / 4 KB
  __shared__ float comb[(NOUT==32) ? 64*33 : 1];            // 8.4 KB (NOUT=32)

  const int tid  = threadIdx.x;
  const int lane = tid & 63;
  const int w    = tid >> 6;
  const int c16  = lane & 15;
  const int g    = lane >> 4;
  const int m0   = blockIdx.x * MT;
  const int mbase = (NOUT==128) ? ((w>>2)<<5) : ((w>>1)<<4);
  const int nbase = (NOUT==128) ? ((w&3)<<5) : ((w&1)<<4);

  *(int2*)&cmap_s[tid<<1] = *(const int2*)(cmap + m0*16 + (tid<<1));
  __syncthreads();

#define STAGE(KC, BUF) do { \
  const int kc_ = (KC); \
  { \
    int m_ = tid>>3, u_ = tid&7; \
    int cm_ = cmap_s[(m_<<4) + (kc_>>1)]; \
    glds16((const char*)base + ((size_t)cm_<<8) + ((kc_&1)<<7) + ((u_ ^ (m_&7))<<4), \
           &A_s[BUF][tid<<3]); \
  } \
  if constexpr (NOUT==128) { \
    int n_ = tid>>3, u_ = tid&7; \
    glds16((const char*)Wt + ((size_t)((kc_>>1)*128 + n_)<<8) + ((kc_&1)<<7) + ((u_ ^ (n_&7))<<4), \
           &B_s[BUF][tid<<3]); \
  } else { \
    if (w < 4) { \
      int uid_ = (w<<6) + lane; \
      int n_ = uid_>>3, u_ = uid_&7; \
      glds16((const char*)Wt + ((size_t)((kc_>>1)*32 + n_)<<8) + ((kc_&1)<<7) + ((u_ ^ (n_&7))<<4), \
             &B_s[BUF][uid_<<3]); } \
  } \
} while(0)

// per-wave loads/stage: NOUT=128 -> 2 (A+B); NOUT=32 -> w<4: 2, w>=4: 1.
#define WAIT_MAIN do { \
  if constexpr (NOUT==128) { asm volatile("s_waitcnt vmcnt(4)" ::: "memory"); } \
  else { if (w < 4) asm volatile("s_waitcnt vmcnt(4)" ::: "memory"); \
         else       asm volatile("s_waitcnt vmcnt(2)" ::: "memory"); } \
} while(0)
#define WAIT_T1 do { \
  if constexpr (NOUT==128) { asm volatile("s_waitcnt vmcnt(2)" ::: "memory"); } \
  else { if (w < 4) asm volatile("s_waitcnt vmcnt(2)" ::: "memory"); \
         else       asm volatile("s_waitcnt vmcnt(1)" ::: "memory"); } \
} while(0)

  f32x4 acc[MI][NIw];
  #pragma unroll
  for (int mi=0; mi<MI; ++mi)
    #pragma unroll
    for (int ni=0; ni<NIw; ++ni)
      acc[mi][ni] = f32x4{0.f,0.f,0.f,0.f};

#define COMPUTE(BUF) do { \
  _Pragma("unroll") \
  for (int kk=0; kk<2; ++kk) { \
    short8 af[MI], bfr[NIw]; \
    _Pragma("unroll") \
    for (int mi=0; mi<MI; ++mi) { \
      int m_ = mbase + mi*16 + c16; \
      af[mi] = *(const short8*)((const char*)&A_s[BUF][0] + m_*128 \
               + (((kk<<6) + (g<<4)) ^ ((m_&7)<<4))); } \
    _Pragma("unroll") \
    for (int ni=0; ni<NIw; ++ni) { \
      int n_ = nbase + ni*16 + c16; \
      bfr[ni] = *(const short8*)((const char*)&B_s[BUF][0] + n_*128 \
               + (((kk<<6) + (g<<4)) ^ ((n_&7)<<4))); } \
    _Pragma("unroll") \
    for (int mi=0; mi<MI; ++mi) \
      _Pragma("unroll") \
      for (int ni=0; ni<NIw; ++ni) \
        acc[mi][ni] = __builtin_amdgcn_mfma_f32_16x16x32_bf16(af[mi], bfr[ni], acc[mi][ni], 0,0,0); \
  } \
} while(0)

  STAGE(0, 0);
  STAGE(1, 1);
  for (int kc = 0; kc < 30; ++kc) {
    STAGE(kc+2, (kc+2)%3);
    WAIT_MAIN;
    __builtin_amdgcn_s_barrier();
    COMPUTE(kc%3);
    asm volatile("s_waitcnt lgkmcnt(0)" ::: "memory");
    __builtin_amdgcn_s_barrier();
  }
  // kc = 30
  WAIT_T1;
  __builtin_amdgcn_s_barrier();
  COMPUTE(0);
  asm volatile("s_waitcnt lgkmcnt(0)" ::: "memory");
  __builtin_amdgcn_s_barrier();
  // kc = 31
  asm volatile("s_waitcnt vmcnt(0)" ::: "memory");
  __builtin_amdgcn_s_barrier();
  COMPUTE(1);

  if constexpr (NOUT == 128) {
    #pragma unroll
    for (int mi=0; mi<MI; ++mi)
      #pragma unroll
      for (int ni=0; ni<NIw; ++ni)
        #pragma unroll
        for (int j=0; j<4; ++j) {
          int row = mbase + mi*16 + (g<<2) + j;
          int col = nbase + ni*16 + c16;
          h_out[((size_t)(m0+row)<<7) + col] = f2bf(fmaxf(acc[mi][ni][j], 0.f));
        }
  } else {
    #pragma unroll
    for (int j=0; j<4; ++j)
      comb[(mbase + (g<<2) + j)*33 + nbase + c16] = acc[0][0][j];
    __syncthreads();
    if (tid < 64) {
      const int row = tid;
      float v[32];
      #pragma unroll
      for (int c=0; c<32; ++c) v[c] = comb[row*33 + c];
      float mx = v[0];
      #pragma unroll
      for (int c=1; c<32; ++c) mx = fmaxf(mx, v[c]);
      float sm = 0.f;
      #pragma unroll
      for (int c=0; c<32; ++c){ v[c] = __expf(v[c]-mx); sm += v[c]; }
      float sc = mobj[m0+row] / sm;
      float4* op = (float4*)(out + ((size_t)(m0+row)<<5));
      #pragma unroll
      for (int c=0; c<8; ++c)
        op[c] = make_float4(v[4*c]*sc, v[4*c+1]*sc, v[4*c+2]*sc, v[4*c+3]*sc);
    }
  }
#undef STAGE
#undef WAIT_MAIN
#undef WAIT_T1
#undef COMPUTE
}

extern "C" void kernel_launch(void* const* d_in, const int* in_sizes, int n_in,
                              void* d_out, int out_size, void* d_ws, size_t ws_size,
                              hipStream_t stream){
  const int*   cls   = (const int*)  d_in[0];
  // d_in[1] states_objects: unused by reference
  const int*   et    = (const int*)  d_in[2];
  const int*   ec    = (const int*)  d_in[3];
  const float* mobj  = (const float*)d_in[4];
  const float* medge = (const float*)d_in[5];
  const float* emb   = (const float*)d_in[6];
  const float* W1    = (const float*)d_in[7];
  const float* W2    = (const float*)d_in[8];
  const float* W3    = (const float*)d_in[9];
  float* out = (float*)d_out;

  char* ws = (char*)d_ws;
  size_t o = 0;
  auto alloc = [&](size_t bytes)->char*{
    char* p = ws + o;
    o += (bytes + 255) & ~(size_t)255;
    return p;
  };
  unsigned short* hA    = (unsigned short*)alloc((size_t)B_*N_*H_*2);   // 8 MB
  unsigned short* hB    = (unsigned short*)alloc((size_t)B_*N_*H_*2);   // 8 MB
  unsigned short* W1t   = (unsigned short*)alloc((size_t)R_*H_*H_*2);   // 4 MB
  unsigned short* W2t   = (unsigned short*)alloc((size_t)R_*H_*H_*2);   // 4 MB
  unsigned short* W3t   = (unsigned short*)alloc((size_t)R_*OUT_*H_*2); // 1 MB
  int*            head  = (int*)alloc((size_t)NKEYS*4);                 // 2 MB
  unsigned*       link  = (unsigned*)alloc((size_t)NEDGE*4);            // 2 MB
  int*            cmapA = (int*)alloc((size_t)NKEYS*4);                 // 2 MB
  int*            cmapB = (int*)alloc((size_t)NKEYS*4);                 // 2 MB
  unsigned short* aggc  = (unsigned short*)alloc(((size_t)NKEYS+1)*H_*2); // 128 MB
  (void)ws_size; (void)in_sizes; (void)n_in; (void)out_size;

  const int hARow   = (int)(((char*)hA   - ws) >> 8);   // 0
  const int hBRow   = (int)(((char*)hB   - ws) >> 8);
  const int aggcRow = (int)(((char*)aggc - ws) >> 8);
  const unsigned short* vbase = (const unsigned short*)ws;

  // edge chains + virtual-row maps (replaces hist/scan/fill counting sort)
  hipMemsetAsync(head, 0xFF, (size_t)NKEYS*4, stream);
  hipLaunchKernelGGL(link_k, dim3(NEDGE/256), dim3(256), 0, stream, et, ec, head, link);
  hipLaunchKernelGGL(cmap_k, dim3(NKEYS/256), dim3(256), 0, stream, head, link, medge,
                     cmapA, cmapB, hARow, hBRow, aggcRow);

  // h0 = bf16(embed[class]);  W -> bf16 [r][n][k];  zero slot 0 of aggc
  hipLaunchKernelGGL(prep_k, dim3((B_*N_*32 + 2*R_*H_*H_ + R_*OUT_*H_)/256), dim3(256), 0, stream,
                     cls, emb, W1, W2, W3, hA, W1t, W2t, W3t, aggc);

  const int aggGrid = (NKEYS*4)/256;   // 8192
  const int g128    = (B_*N_)/128;     // 256 blocks x 1024 thr
  const int g32     = (B_*N_)/64;      // 512 blocks x 512 thr

  // layer 1 (h = hA, zero-copy rows via cmapA)
  hipLaunchKernelGGL(agg_k, dim3(aggGrid), dim3(256), 0, stream, hA, head, link, medge, aggc);
  hipLaunchKernelGGL((gemm_k<128>), dim3(g128), dim3(1024), 0, stream,
                     vbase, cmapA, W1t, (const float*)nullptr, hB, (float*)nullptr);
  // layer 2 (h = hB)
  hipLaunchKernelGGL(agg_k, dim3(aggGrid), dim3(256), 0, stream, hB, head, link, medge, aggc);
  hipLaunchKernelGGL((gemm_k<128>), dim3(g128), dim3(1024), 0, stream,
                     vbase, cmapB, W2t, (const float*)nullptr, hA, (float*)nullptr);
  // layer 3 (h = hA, + fused softmax * mask)
  hipLaunchKernelGGL(agg_k, dim3(aggGrid), dim3(256), 0, stream, hA, head, link, medge, aggc);
  hipLaunchKernelGGL((gemm_k<32>), dim3(g32), dim3(512), 0, stream,
                     vbase, cmapA, W3t, mobj, (unsigned short*)nullptr, out);
}